// Round 18
// baseline (289.499 us; speedup 1.0000x reference)
//
#include <hip/hip_runtime.h>
#include <hip/hip_bf16.h>

#define LRELU(x) ((x) >= 0.f ? (x) : 0.01f * (x))

typedef __attribute__((ext_vector_type(8))) short short8v;
typedef __attribute__((ext_vector_type(4))) float f32x4;

__device__ inline unsigned fenc(float x) {
    unsigned u = __float_as_uint(x);
    return (u & 0x80000000u) ? ~u : (u | 0x80000000u);
}
__device__ inline float fdec(unsigned e) {
    return __uint_as_float((e & 0x80000000u) ? (e ^ 0x80000000u) : ~e);
}

__device__ inline float wred(float v) {
#pragma unroll
    for (int o = 32; o > 0; o >>= 1) v += __shfl_xor(v, o, 64);
    return v;
}
__device__ inline float wredmax(float v) {
#pragma unroll
    for (int o = 32; o > 0; o >>= 1) v = fmaxf(v, __shfl_xor(v, o, 64));
    return v;
}

__device__ inline unsigned short f2bu(float x) {
    __hip_bfloat16 b = __float2bfloat16(x);
    return *reinterpret_cast<unsigned short*>(&b);
}
__device__ inline float bu2f(unsigned short u) {
    return __uint_as_float((unsigned)u << 16);
}

__device__ inline f32x4 mfma16(short8v a, short8v b, f32x4 c) {
    return __builtin_amdgcn_mfma_f32_16x16x32_bf16(a, b, c, 0, 0, 0);
}

// async global->LDS, 16B per lane, dest = (wave-uniform base) + lane*16
__device__ inline void gload16(const void* g, void* l) {
    __builtin_amdgcn_global_load_lds(
        (const __attribute__((address_space(1))) void*)g,
        (__attribute__((address_space(3))) void*)l, 16, 0, 0);
}

// ---- convert W matrices to transposed bf16: Wt[n][k] = bf16(W[k][n]) ----
__global__ __launch_bounds__(256) void k_convW(
    const float* __restrict__ wh, const float* __restrict__ wt,
    const float* __restrict__ hww, unsigned short* __restrict__ wtb_hi,
    unsigned short* __restrict__ hwt_hi) {
    int id = blockIdx.x * 256 + threadIdx.x;
    if (id < 256 * 256) {
        int n = id >> 8, k = id & 255;
        float v = (n < 128) ? wh[(size_t)k * 128 + n] : wt[(size_t)k * 128 + (n - 128)];
        wtb_hi[(size_t)n * 256 + k] = f2bu(v);
    } else {
        int id2 = id - 256 * 256;
        if (id2 < 128 * 128) {
            int n = id2 >> 7, k = id2 & 127;
            hwt_hi[(size_t)n * 128 + k] = f2bu(hww[(size_t)k * 128 + n]);
        }
    }
}

// ---- relation dot: er2[r] = r_emb[r]·a_r2 ----
__global__ __launch_bounds__(256) void k_rel(const float* __restrict__ remb,
                                             const float* __restrict__ ar2,
                                             float* __restrict__ er2, int NR) {
    int lane = threadIdx.x & 63;
    int r = blockIdx.x * 4 + (threadIdx.x >> 6);
    if (r >= NR) return;
    float v0 = remb[(size_t)r * 128 + lane];
    float v1 = remb[(size_t)r * 128 + 64 + lane];
    float p2 = wred(v0 * ar2[lane] + v1 * ar2[64 + lane]);
    if (lane == 0) er2[r] = p2;
}

// ---- 2-phase double-buffered LDS-staged MFMA GEMM ----
// Block 128x128; row-wave tiling (wave w: rows w*32..+31, all 128 cols,
// acc[2][8]); 16 MFMA/step; ONE barrier/step.
// EPI 0 (proj, KD=256): A staged into LDS AS F32 via global_load_lds (fully
//   async, no reg round-trip); f32->bf16 conversion happens at fragment-read
//   time inside the MFMA phase. B bf16 via global_load_lds.
//   half0 -> oh0=bf16(relu(xe@wh)), hb, eh4o;
//   half1 -> oh1=bf16(relu(xe@wt)*inv) pre-normalized, pta={ta, tidx[row]}.
// EPI 1 (highway, KD=128, A bf16): gate=sigmoid(C+bias);
//   o0 = g*(m3[row]?xeh:0) + (1-g)*bf16(A)  -- skips xeh load for untouched rows.
template <int EPI>
__device__ __forceinline__ void mm_body(
    const float* __restrict__ Af32, const unsigned short* __restrict__ Ah,
    const unsigned short* __restrict__ Bh,
    unsigned short* __restrict__ oh0, unsigned short* __restrict__ oh1,
    float* __restrict__ o0, const float* __restrict__ bias,
    const float* __restrict__ xeh, const unsigned* __restrict__ m3f, int M,
    const float* __restrict__ ah2, const float* __restrict__ ah3,
    const float* __restrict__ ah4, const float* __restrict__ at2,
    const float* __restrict__ at3,
    float* __restrict__ hb, float* __restrict__ eh4o,
    float2* __restrict__ pta, const int* __restrict__ tidxg) {
    constexpr int KD = (EPI == 0) ? 256 : 128;
    constexpr int NSTEP = KD / 32;
    __shared__ float As_f[(EPI == 0) ? 2 : 1][(EPI == 0) ? 128 * 32 : 16];
    __shared__ unsigned short As_h[(EPI == 1) ? 2 : 1][(EPI == 1) ? 128 * 32 : 16];
    __shared__ unsigned short Bs_h[2][128 * 32];

    int bx = blockIdx.x;
    int half = (EPI == 0) ? (bx & 1) : 0;
    int mblk = (EPI == 0) ? (bx >> 1) : bx;
    int row0 = mblk * 128;
    if (row0 + 128 > M) row0 = M - 128;
    int tid = threadIdx.x, w = tid >> 6, l = tid & 63;
    int lr = l & 15, hi4 = l >> 4;
    int srow = l >> 2, sslot = l & 3;      // bf16 unit: 16 rows, 4x16B/row
    int arow = l >> 3, afi = l & 7;        // f32 unit: 8 rows, 8x16B/row

    f32x4 acc[2][8];
#pragma unroll
    for (int i = 0; i < 2; i++)
#pragma unroll
        for (int j = 0; j < 8; j++) acc[i][j] = (f32x4){0.f, 0.f, 0.f, 0.f};

    auto stage = [&](int s, int b) {
        int k0 = s * 32;
        constexpr int NU = (EPI == 0) ? 6 : 4;  // EPI0: 16 A-f32 + 8 B; EPI1: 8+8
#pragma unroll
        for (int i = 0; i < NU; i++) {
            int u = w * NU + i;
            if constexpr (EPI == 0) {
                if (u < 16) {  // A f32 unit: 1KB, 8 rows of 128B
                    int row = u * 8 + arow;
                    int gi = afi >> 1, hf = afi & 1;
                    int sf = ((gi ^ ((row >> 1) & 3)) << 3) + (hf << 2);
                    gload16(Af32 + (size_t)(row0 + row) * KD + k0 + sf,
                            (char*)&As_f[b][0] + u * 1024);
                } else {       // B bf16 unit: 1KB, 16 rows of 64B
                    int ub = u - 16;
                    int row = ub * 16 + srow;
                    int klog = (sslot ^ ((row >> 1) & 3)) * 8;
                    gload16(Bh + (size_t)(half * 128 + row) * KD + k0 + klog,
                            (char*)&Bs_h[b][0] + ub * 1024);
                }
            } else {
                int arr = u >> 3, ld = u & 7;
                int row = ld * 16 + srow;
                int klog = (sslot ^ ((row >> 1) & 3)) * 8;
                if (arr == 0)
                    gload16(Ah + (size_t)(row0 + row) * KD + k0 + klog,
                            (char*)&As_h[b][0] + ld * 1024);
                else
                    gload16(Bh + (size_t)row * KD + k0 + klog,
                            (char*)&Bs_h[b][0] + ld * 1024);
            }
        }
    };

    stage(0, 0);
    __syncthreads();                              // buf0 ready
    for (int s = 0; s < NSTEP; s++) {
        int b = s & 1;
        if (s + 1 < NSTEP) stage(s + 1, b ^ 1);  // all loads fly under compute

        short8v am_h[2];
#pragma unroll
        for (int mr = 0; mr < 2; mr++) {
            int r = w * 32 + mr * 16 + lr;
            int ko = (hi4 ^ ((r >> 1) & 3)) * 8;
            if constexpr (EPI == 0) {
                float4 f0 = *(const float4*)&As_f[b][r * 32 + ko];
                float4 f1 = *(const float4*)&As_f[b][r * 32 + ko + 4];
                short8v v;
                v[0] = (short)f2bu(f0.x); v[1] = (short)f2bu(f0.y);
                v[2] = (short)f2bu(f0.z); v[3] = (short)f2bu(f0.w);
                v[4] = (short)f2bu(f1.x); v[5] = (short)f2bu(f1.y);
                v[6] = (short)f2bu(f1.z); v[7] = (short)f2bu(f1.w);
                am_h[mr] = v;
            } else {
                am_h[mr] = *(const short8v*)&As_h[b][r * 32 + ko];
            }
        }
#pragma unroll
        for (int ncc = 0; ncc < 8; ncc += 4) {   // split B loads: cap VGPR
            short8v bn_h[4];
#pragma unroll
            for (int j = 0; j < 4; j++) {
                int n = (ncc + j) * 16 + lr;
                int ko = (hi4 ^ ((n >> 1) & 3)) * 8;
                bn_h[j] = *(const short8v*)&Bs_h[b][n * 32 + ko];
            }
#pragma unroll
            for (int mr = 0; mr < 2; mr++)
#pragma unroll
                for (int j = 0; j < 4; j++)
                    acc[mr][ncc + j] = mfma16(am_h[mr], bn_h[j], acc[mr][ncc + j]);
        }
        __syncthreads();  // drains next-buf loads + protects buffer swap
    }

    if constexpr (EPI == 0) {
        unsigned short* OH = half ? oh1 : oh0;
        const float* v1 = half ? at2 : ah2;
        const float* v2 = half ? at3 : ah3;
#pragma unroll
        for (int mr = 0; mr < 2; mr++)
#pragma unroll
            for (int rr = 0; rr < 4; rr++) {
                int row = row0 + w * 32 + mr * 16 + hi4 * 4 + rr;
                float d0 = 0.f, d1 = 0.f, d2 = 0.f;
#pragma unroll
                for (int nc = 0; nc < 8; nc++) {
                    float v = fmaxf(acc[mr][nc][rr], 0.f);
                    int col = nc * 16 + lr;
                    d0 = fmaf(v, v1[col], d0);
                    d1 = fmaf(v, v2[col], d1);
                    d2 = half ? fmaf(v, v, d2) : fmaf(v, ah4[col], d2);
                }
#pragma unroll
                for (int o = 1; o <= 8; o <<= 1) {   // reduce within 16-lane group
                    d0 += __shfl_xor(d0, o, 64);
                    d1 += __shfl_xor(d1, o, 64);
                    d2 += __shfl_xor(d2, o, 64);
                }
                float inv = 1.f;
                if (half) inv = 1.f / fmaxf(sqrtf(d2), 1e-12f);
#pragma unroll
                for (int nc = 0; nc < 8; nc++) {
                    float v = fmaxf(acc[mr][nc][rr], 0.f);
                    OH[(size_t)row * 128 + nc * 16 + lr] = f2bu(half ? v * inv : v);
                }
                if (lr == 0) {
                    if (half == 0) {
                        hb[row] = d0 + 0.25f * d1;
                        eh4o[row] = d2;
                    } else {
                        float tav = (d0 + 0.25f * d1) * inv;
                        pta[row] = make_float2(tav, __int_as_float(tidxg[row]));
                    }
                }
            }
    } else {
#pragma unroll
        for (int mr = 0; mr < 2; mr++)
#pragma unroll
            for (int rr = 0; rr < 4; rr++) {
                int row = row0 + w * 32 + mr * 16 + hi4 * 4 + rr;
                bool touched = (m3f[row] != 0u);   // uniform per 16-lane group
#pragma unroll
                for (int nc = 0; nc < 8; nc++) {
                    int col = nc * 16 + lr;
                    float a = acc[mr][nc][rr] + bias[col];
                    float g = 1.f / (1.f + expf(-a));
                    size_t o = (size_t)row * 128 + col;
                    float af = bu2f(Ah[o]);
                    float xv = 0.f;
                    if (touched) xv = xeh[o];
                    o0[o] = g * xv + (1.f - g) * af;
                }
            }
    }
}

__global__ __launch_bounds__(256) void k_mm_proj(
    const float* Af32, const unsigned short* Bh,
    unsigned short* oh0, unsigned short* oh1, int M,
    const float* ah2, const float* ah3, const float* ah4,
    const float* at2, const float* at3,
    float* hb, float* eh4o, float2* pta, const int* tidxg) {
    mm_body<0>(Af32, nullptr, Bh, oh0, oh1, nullptr, nullptr, nullptr, nullptr,
               M, ah2, ah3, ah4, at2, at3, hb, eh4o, pta, tidxg);
}

__global__ __launch_bounds__(256) void k_mm_hw(
    const unsigned short* Ah, const unsigned short* Bh,
    float* o0, const float* bias, const float* xeh, const unsigned* m3f, int M) {
    mm_body<1>(nullptr, Ah, Bh, nullptr, nullptr, o0, bias, xeh, m3f, M,
               nullptr, nullptr, nullptr, nullptr, nullptr,
               nullptr, nullptr, nullptr, nullptr);
}

// ---- counting sort by class_index ----
__global__ __launch_bounds__(256) void k_hist(const int* __restrict__ cidx,
                                              int* __restrict__ cnt, int E) {
    int i = blockIdx.x * 256 + threadIdx.x;
    if (i >= E) return;
    atomicAdd(&cnt[cidx[i]], 1);
}

__global__ __launch_bounds__(1024) void k_scan(const int* __restrict__ cnt,
                                               int* __restrict__ off,
                                               int* __restrict__ cur, int NC) {
    __shared__ int wt[16];
    __shared__ int sbase;
    int tid = threadIdx.x, w = tid >> 6, lane = tid & 63;
    if (tid == 0) sbase = 0;
    __syncthreads();
    for (int c0 = 0; c0 < NC; c0 += 1024) {
        int c = c0 + tid;
        int v = (c < NC) ? cnt[c] : 0;
        int x = v;
#pragma unroll
        for (int o = 1; o < 64; o <<= 1) {
            int t = __shfl_up(x, o, 64);
            if (lane >= o) x += t;
        }
        if (lane == 63) wt[w] = x;
        __syncthreads();
        int pre = 0, tot = 0;
#pragma unroll
        for (int i = 0; i < 16; i++) {
            int t = wt[i];
            tot += t;
            if (i < w) pre += t;
        }
        int excl = sbase + pre + x - v;
        if (c < NC) { off[c] = excl; cur[c] = excl; }
        __syncthreads();
        if (tid == 0) sbase += tot;
        __syncthreads();
    }
}

// ---- fused level-2 logit + scatter (packed 8B gather + packed 8B write) ----
// z2 = lrelu(pta[te].ta + hb[h] + 0.5*er2[rel]); g = pta[te].g
__global__ __launch_bounds__(256) void k_edgescatter(
    const int* __restrict__ cidx, int* __restrict__ cur,
    const int* __restrict__ hidx, const int* __restrict__ tidx,
    const int* __restrict__ rel, const float2* __restrict__ pta,
    const float* __restrict__ hb, const float* __restrict__ er2,
    float2* __restrict__ e2gs, int E) {
    int i = blockIdx.x * 256 + threadIdx.x;
    if (i >= E) return;
    int pos = atomicAdd(&cur[cidx[i]], 1);
    float2 p = pta[tidx[i]];
    float z2 = p.x + hb[hidx[i]] + 0.5f * er2[rel[i]];
    e2gs[pos] = make_float2(LRELU(z2), p.y);
}

// ---- fused level-2 softmax + spmm + class-dot, one wave/class ----
__global__ __launch_bounds__(256) void k_spmm2(
    const int* __restrict__ off, const int* __restrict__ cnt,
    const float2* __restrict__ e2gs, const unsigned* __restrict__ xrtn_b,
    float* __restrict__ xclass, const float* __restrict__ ac,
    const float* __restrict__ eh4, const int* __restrict__ hclass,
    float* __restrict__ zc, unsigned* __restrict__ m3, int NC) {
    int lane = threadIdx.x & 63;
    int c = blockIdx.x * 4 + (threadIdx.x >> 6);
    if (c >= NC) return;
    int n = cnt[c];
    float a0 = 0.f, a1 = 0.f;
    if (n > 0) {
        int base = off[c];
        float m = -3.4e38f, s = 0.f;
        for (int j = lane; j < n; j += 64) {
            float z = e2gs[base + j].x;
            if (z > m) { s = s * __expf(m - z) + 1.f; m = z; }
            else s += __expf(z - m);
        }
        float M = wredmax(m);
        s = wred(s * __expf(m - M));
        float inv = 1.f / (s + 1e-16f);
        for (int j0 = 0; j0 < n; j0 += 64) {
            int lim = n - j0;
            if (lim > 64) lim = 64;
            float wv = 0.f;
            int g = 0;
            if (lane < lim) {
                float2 pg = e2gs[base + j0 + lane];
                wv = __expf(pg.x - M) * inv;
                g = __float_as_int(pg.y);
            }
            int jj = 0;
            for (; jj + 8 <= lim; jj += 8) {  // 8 rows in flight, 256B each
                float w0 = __shfl(wv, jj + 0), w1 = __shfl(wv, jj + 1);
                float w2 = __shfl(wv, jj + 2), w3 = __shfl(wv, jj + 3);
                float w4 = __shfl(wv, jj + 4), w5 = __shfl(wv, jj + 5);
                float w6 = __shfl(wv, jj + 6), w7 = __shfl(wv, jj + 7);
                unsigned u0 = xrtn_b[(size_t)__shfl(g, jj + 0) * 64 + lane];
                unsigned u1 = xrtn_b[(size_t)__shfl(g, jj + 1) * 64 + lane];
                unsigned u2 = xrtn_b[(size_t)__shfl(g, jj + 2) * 64 + lane];
                unsigned u3 = xrtn_b[(size_t)__shfl(g, jj + 3) * 64 + lane];
                unsigned u4 = xrtn_b[(size_t)__shfl(g, jj + 4) * 64 + lane];
                unsigned u5 = xrtn_b[(size_t)__shfl(g, jj + 5) * 64 + lane];
                unsigned u6 = xrtn_b[(size_t)__shfl(g, jj + 6) * 64 + lane];
                unsigned u7 = xrtn_b[(size_t)__shfl(g, jj + 7) * 64 + lane];
                a0 = fmaf(w0, bu2f((unsigned short)(u0 & 0xffff)), a0);
                a1 = fmaf(w0, bu2f((unsigned short)(u0 >> 16)), a1);
                a0 = fmaf(w1, bu2f((unsigned short)(u1 & 0xffff)), a0);
                a1 = fmaf(w1, bu2f((unsigned short)(u1 >> 16)), a1);
                a0 = fmaf(w2, bu2f((unsigned short)(u2 & 0xffff)), a0);
                a1 = fmaf(w2, bu2f((unsigned short)(u2 >> 16)), a1);
                a0 = fmaf(w3, bu2f((unsigned short)(u3 & 0xffff)), a0);
                a1 = fmaf(w3, bu2f((unsigned short)(u3 >> 16)), a1);
                a0 = fmaf(w4, bu2f((unsigned short)(u4 & 0xffff)), a0);
                a1 = fmaf(w4, bu2f((unsigned short)(u4 >> 16)), a1);
                a0 = fmaf(w5, bu2f((unsigned short)(u5 & 0xffff)), a0);
                a1 = fmaf(w5, bu2f((unsigned short)(u5 >> 16)), a1);
                a0 = fmaf(w6, bu2f((unsigned short)(u6 & 0xffff)), a0);
                a1 = fmaf(w6, bu2f((unsigned short)(u6 >> 16)), a1);
                a0 = fmaf(w7, bu2f((unsigned short)(u7 & 0xffff)), a0);
                a1 = fmaf(w7, bu2f((unsigned short)(u7 >> 16)), a1);
            }
            for (; jj < lim; jj++) {
                float wj = __shfl(wv, jj);
                unsigned u = xrtn_b[(size_t)__shfl(g, jj) * 64 + lane];
                a0 = fmaf(wj, bu2f((unsigned short)(u & 0xffff)), a0);
                a1 = fmaf(wj, bu2f((unsigned short)(u >> 16)), a1);
            }
        }
    }
    *(float2*)&xclass[(size_t)c * 128 + 2 * lane] = make_float2(a0, a1);
    // fused class-level dot: e_c = xclass[c]·ac + eh4[hclass[c]]
    float p = wred(a0 * ac[2 * lane] + a1 * ac[2 * lane + 1]);
    if (lane == 0) {
        int hc = hclass[c];
        float z = LRELU(p + eh4[hc]);
        zc[c] = z;
        atomicMax(&m3[hc], fenc(z));
    }
}

// ---- level 3: class -> head entity ----
// Wave per class: zero xeh[hc] (idempotent; runs before class3's atomics),
// lane 0 finalizes exp and accumulates s3.
__global__ __launch_bounds__(256) void k_class2(
    const int* __restrict__ hclass, float* __restrict__ zc,
    const unsigned* __restrict__ m3, float* __restrict__ s3,
    float* __restrict__ xeh, int NC) {
    int lane = threadIdx.x & 63;
    int c = blockIdx.x * 4 + (threadIdx.x >> 6);
    if (c >= NC) return;
    int hc = hclass[c];
    *(float2*)&xeh[(size_t)hc * 128 + 2 * lane] = make_float2(0.f, 0.f);
    if (lane == 0) {
        float ex = expf(zc[c] - fdec(m3[hc]));
        zc[c] = ex;
        atomicAdd(&s3[hc], ex);
    }
}

__global__ __launch_bounds__(256) void k_class3(
    const int* __restrict__ hclass, const float* __restrict__ zc,
    const float* __restrict__ s3, const float* __restrict__ xclass,
    float* __restrict__ xeh, int NC) {
    int lane = threadIdx.x & 63;
    int c = blockIdx.x * 4 + (threadIdx.x >> 6);
    if (c >= NC) return;
    int hc = hclass[c];
    float gama = zc[c] / (s3[hc] + 1e-16f);
    float v0 = xclass[(size_t)c * 128 + lane], v1 = xclass[(size_t)c * 128 + 64 + lane];
    atomicAdd(&xeh[(size_t)hc * 128 + lane], gama * v0);
    atomicAdd(&xeh[(size_t)hc * 128 + 64 + lane], gama * v1);
}

extern "C" void kernel_launch(void* const* d_in, const int* in_sizes, int n_in,
                              void* d_out, int out_size, void* d_ws, size_t ws_size,
                              hipStream_t stream) {
    (void)n_in; (void)out_size; (void)ws_size;
    const float* xe   = (const float*)d_in[0];
    const int*   eidx = (const int*)d_in[1];
    const int*   rel  = (const int*)d_in[2];
    const float* remb = (const float*)d_in[4];
    const int*   cidx = (const int*)d_in[5];
    const int*   hcls = (const int*)d_in[6];
    const float* ah2  = (const float*)d_in[8];
    const float* ah3  = (const float*)d_in[9];
    const float* ah4  = (const float*)d_in[10];
    const float* at2  = (const float*)d_in[12];
    const float* at3  = (const float*)d_in[13];
    const float* ar2  = (const float*)d_in[15];
    const float* ac   = (const float*)d_in[16];
    const float* wh   = (const float*)d_in[17];
    const float* wt   = (const float*)d_in[18];
    const float* hww  = (const float*)d_in[19];
    const float* hwb  = (const float*)d_in[20];
    float* out = (float*)d_out;

    const int NE = in_sizes[0] / 256;
    const int E  = in_sizes[2];
    const int NR = in_sizes[4] / 128;
    const int NC = in_sizes[6];
    const int* hidx = eidx;
    const int* tidx = eidx + E;

    char* base = (char*)d_ws;
    size_t off0 = 0;
    auto alloc = [&](size_t bytes) -> char* {
        char* r = base + off0;
        off0 = (off0 + bytes + 255) & ~(size_t)255;
        return r;
    };
    float* hb   = (float*)alloc((size_t)NE * 4);
    float* eh4b = (float*)alloc((size_t)NE * 4);
    float2* pta = (float2*)alloc((size_t)NE * 8);
    float* er2b = (float*)alloc((size_t)NR * 4);
    float2* e2gs = (float2*)alloc((size_t)E * 8);
    float* zc   = (float*)alloc((size_t)NC * 4);
    unsigned short* wtb_hi = (unsigned short*)alloc((size_t)256 * 256 * 2);
    unsigned short* hwt_hi = (unsigned short*)alloc((size_t)128 * 128 * 2);
    unsigned short* xrh_hi = (unsigned short*)alloc((size_t)NE * 128 * 2);
    unsigned short* xrtn   = (unsigned short*)alloc((size_t)NE * 128 * 2);
    int* offb = (int*)alloc((size_t)NC * 4);
    int* curb = (int*)alloc((size_t)NC * 4);
    float* xclass = (float*)alloc((size_t)NC * 128 * 4);
    float* xeh    = (float*)alloc((size_t)NE * 128 * 4);  // NOT memset: rows
    // zeroed per-launch by k_class2 for touched hc only; untouched rows are
    // never read (m3[row]==0 guard in k_mm_hw).
    size_t zoff = off0;  // everything below is zero-initialized per launch
    unsigned* m3 = (unsigned*)alloc((size_t)NE * 4);
    float* s3    = (float*)alloc((size_t)NE * 4);
    int* cntb    = (int*)alloc((size_t)NC * 4);
    size_t zbytes = off0 - zoff;

    hipMemsetAsync(base + zoff, 0, zbytes, stream);

    k_convW<<<(256 * 256 + 128 * 128 + 255) / 256, 256, 0, stream>>>(
        wh, wt, hww, wtb_hi, hwt_hi);
    k_rel<<<(NR + 3) / 4, 256, 0, stream>>>(remb, ar2, er2b, NR);

    // projection GEMM: A staged to LDS as f32 (async), cvt at fragment read;
    // bf16 mirrors (xrt pre-normalized) + fused dots + packed pta records
    k_mm_proj<<<((NE + 127) / 128) * 2, 256, 0, stream>>>(
        xe, wtb_hi, xrh_hi, xrtn, NE,
        ah2, ah3, ah4, at2, at3, hb, eh4b, pta, tidx);

    // class-CSR histogram/scan
    k_hist<<<(E + 255) / 256, 256, 0, stream>>>(cidx, cntb, E);
    k_scan<<<1, 1024, 0, stream>>>(cntb, offb, curb, NC);

    // fused level-2 logit + scatter (level-1 softmax cancels vs F.normalize)
    k_edgescatter<<<(E + 255) / 256, 256, 0, stream>>>(
        cidx, curb, hidx, tidx, rel, pta, hb, er2b, e2gs, E);

    k_spmm2<<<(NC + 3) / 4, 256, 0, stream>>>(offb, cntb, e2gs,
                                              (const unsigned*)xrtn, xclass,
                                              ac, eh4b, hcls, zc, m3, NC);
    k_class2<<<(NC + 3) / 4, 256, 0, stream>>>(hcls, zc, m3, s3, xeh, NC);
    k_class3<<<(NC + 3) / 4, 256, 0, stream>>>(hcls, zc, s3, xclass, xeh, NC);

    k_mm_hw<<<(NE + 127) / 128, 256, 0, stream>>>(
        xrh_hi, hwt_hi, out, hwb, xeh, m3, NE);
}

// Round 19
// 282.321 us; speedup vs baseline: 1.0254x; 1.0254x over previous
//
#include <hip/hip_runtime.h>
#include <hip/hip_bf16.h>

#define LRELU(x) ((x) >= 0.f ? (x) : 0.01f * (x))

typedef __attribute__((ext_vector_type(8))) short short8v;
typedef __attribute__((ext_vector_type(4))) float f32x4;

__device__ inline unsigned fenc(float x) {
    unsigned u = __float_as_uint(x);
    return (u & 0x80000000u) ? ~u : (u | 0x80000000u);
}
__device__ inline float fdec(unsigned e) {
    return __uint_as_float((e & 0x80000000u) ? (e ^ 0x80000000u) : ~e);
}

__device__ inline float wred(float v) {
#pragma unroll
    for (int o = 32; o > 0; o >>= 1) v += __shfl_xor(v, o, 64);
    return v;
}
__device__ inline float wredmax(float v) {
#pragma unroll
    for (int o = 32; o > 0; o >>= 1) v = fmaxf(v, __shfl_xor(v, o, 64));
    return v;
}

__device__ inline unsigned short f2bu(float x) {
    __hip_bfloat16 b = __float2bfloat16(x);
    return *reinterpret_cast<unsigned short*>(&b);
}
__device__ inline float bu2f(unsigned short u) {
    return __uint_as_float((unsigned)u << 16);
}

__device__ inline f32x4 mfma16(short8v a, short8v b, f32x4 c) {
    return __builtin_amdgcn_mfma_f32_16x16x32_bf16(a, b, c, 0, 0, 0);
}

// async global->LDS, 16B per lane, dest = (wave-uniform base) + lane*16
__device__ inline void gload16(const void* g, void* l) {
    __builtin_amdgcn_global_load_lds(
        (const __attribute__((address_space(1))) void*)g,
        (__attribute__((address_space(3))) void*)l, 16, 0, 0);
}

// ---- convert W matrices to transposed bf16: Wt[n][k] = bf16(W[k][n]) ----
__global__ __launch_bounds__(256) void k_convW(
    const float* __restrict__ wh, const float* __restrict__ wt,
    const float* __restrict__ hww, unsigned short* __restrict__ wtb_hi,
    unsigned short* __restrict__ hwt_hi) {
    int id = blockIdx.x * 256 + threadIdx.x;
    if (id < 256 * 256) {
        int n = id >> 8, k = id & 255;
        float v = (n < 128) ? wh[(size_t)k * 128 + n] : wt[(size_t)k * 128 + (n - 128)];
        wtb_hi[(size_t)n * 256 + k] = f2bu(v);
    } else {
        int id2 = id - 256 * 256;
        if (id2 < 128 * 128) {
            int n = id2 >> 7, k = id2 & 127;
            hwt_hi[(size_t)n * 128 + k] = f2bu(hww[(size_t)k * 128 + n]);
        }
    }
}

// ---- relation dot: er2[r] = r_emb[r]·a_r2 ----
__global__ __launch_bounds__(256) void k_rel(const float* __restrict__ remb,
                                             const float* __restrict__ ar2,
                                             float* __restrict__ er2, int NR) {
    int lane = threadIdx.x & 63;
    int r = blockIdx.x * 4 + (threadIdx.x >> 6);
    if (r >= NR) return;
    float v0 = remb[(size_t)r * 128 + lane];
    float v1 = remb[(size_t)r * 128 + 64 + lane];
    float p2 = wred(v0 * ar2[lane] + v1 * ar2[64 + lane]);
    if (lane == 0) er2[r] = p2;
}

// ---- 2-phase double-buffered LDS-staged MFMA GEMM ----
// Block 128x128; row-wave tiling (wave w: rows w*32..+31, all 128 cols,
// acc[2][8]); 16 MFMA/step; ONE barrier/step.
// EPI 0 (proj, KD=256): A staged to LDS as F32 via global_load_lds with a
//   16B-slot involutive swizzle: lds[row][slot] = global[row][slot^(row&7)]
//   (8 slots/row -> 8 dwords/bank per ds_read = conflict-free). cvt to bf16
//   at fragment-read time. B bf16 (proven conflict-free layout).
//   half0 -> oh0=bf16(relu(xe@wh)), hb, eh4o;
//   half1 -> oh1=bf16(relu(xe@wt)*inv) pre-normalized, pta={ta, tidx[row]}.
// EPI 1 (highway, KD=128, A bf16): gate=sigmoid(C+bias);
//   o0 = g*(m3[row]?xeh:0) + (1-g)*bf16(A).
template <int EPI>
__device__ __forceinline__ void mm_body(
    const float* __restrict__ Af32, const unsigned short* __restrict__ Ah,
    const unsigned short* __restrict__ Bh,
    unsigned short* __restrict__ oh0, unsigned short* __restrict__ oh1,
    float* __restrict__ o0, const float* __restrict__ bias,
    const float* __restrict__ xeh, const unsigned* __restrict__ m3f, int M,
    const float* __restrict__ ah2, const float* __restrict__ ah3,
    const float* __restrict__ ah4, const float* __restrict__ at2,
    const float* __restrict__ at3,
    float* __restrict__ hb, float* __restrict__ eh4o,
    float2* __restrict__ pta, const int* __restrict__ tidxg) {
    constexpr int KD = (EPI == 0) ? 256 : 128;
    constexpr int NSTEP = KD / 32;
    __shared__ float As_f[(EPI == 0) ? 2 : 1][(EPI == 0) ? 128 * 32 : 16];
    __shared__ unsigned short As_h[(EPI == 1) ? 2 : 1][(EPI == 1) ? 128 * 32 : 16];
    __shared__ unsigned short Bs_h[2][128 * 32];

    int bx = blockIdx.x;
    int half = (EPI == 0) ? (bx & 1) : 0;
    int mblk = (EPI == 0) ? (bx >> 1) : bx;
    int row0 = mblk * 128;
    if (row0 + 128 > M) row0 = M - 128;
    int tid = threadIdx.x, w = tid >> 6, l = tid & 63;
    int lr = l & 15, hi4 = l >> 4;
    int srow = l >> 2, sslot = l & 3;      // bf16 unit: 16 rows, 4x16B/row
    int arow = l >> 3, afi = l & 7;        // f32 unit: 8 rows, 8x16B/row

    f32x4 acc[2][8];
#pragma unroll
    for (int i = 0; i < 2; i++)
#pragma unroll
        for (int j = 0; j < 8; j++) acc[i][j] = (f32x4){0.f, 0.f, 0.f, 0.f};

    auto stage = [&](int s, int b) {
        int k0 = s * 32;
        constexpr int NU = (EPI == 0) ? 6 : 4;  // EPI0: 16 A-f32 + 8 B; EPI1: 8+8
#pragma unroll
        for (int i = 0; i < NU; i++) {
            int u = w * NU + i;
            if constexpr (EPI == 0) {
                if (u < 16) {  // A f32 unit: 1KB, 8 rows x 8 16B-slots
                    int row = u * 8 + arow;
                    int sf = ((afi ^ arow) << 2);      // 16B-slot swizzle
                    gload16(Af32 + (size_t)(row0 + row) * KD + k0 + sf,
                            (char*)&As_f[b][0] + u * 1024);
                } else {       // B bf16 unit: 1KB, 16 rows of 64B
                    int ub = u - 16;
                    int row = ub * 16 + srow;
                    int klog = (sslot ^ ((row >> 1) & 3)) * 8;
                    gload16(Bh + (size_t)(half * 128 + row) * KD + k0 + klog,
                            (char*)&Bs_h[b][0] + ub * 1024);
                }
            } else {
                int arr = u >> 3, ld = u & 7;
                int row = ld * 16 + srow;
                int klog = (sslot ^ ((row >> 1) & 3)) * 8;
                if (arr == 0)
                    gload16(Ah + (size_t)(row0 + row) * KD + k0 + klog,
                            (char*)&As_h[b][0] + ld * 1024);
                else
                    gload16(Bh + (size_t)row * KD + k0 + klog,
                            (char*)&Bs_h[b][0] + ld * 1024);
            }
        }
    };

    stage(0, 0);
    __syncthreads();                              // buf0 ready
    for (int s = 0; s < NSTEP; s++) {
        int b = s & 1;
        if (s + 1 < NSTEP) stage(s + 1, b ^ 1);  // all loads fly under compute

        short8v am_h[2];
#pragma unroll
        for (int mr = 0; mr < 2; mr++) {
            int r = w * 32 + mr * 16 + lr;
            if constexpr (EPI == 0) {
                int s0 = ((2 * hi4 + 0) ^ (r & 7)) * 4;
                int s1 = ((2 * hi4 + 1) ^ (r & 7)) * 4;
                float4 f0 = *(const float4*)&As_f[b][r * 32 + s0];
                float4 f1 = *(const float4*)&As_f[b][r * 32 + s1];
                short8v v;
                v[0] = (short)f2bu(f0.x); v[1] = (short)f2bu(f0.y);
                v[2] = (short)f2bu(f0.z); v[3] = (short)f2bu(f0.w);
                v[4] = (short)f2bu(f1.x); v[5] = (short)f2bu(f1.y);
                v[6] = (short)f2bu(f1.z); v[7] = (short)f2bu(f1.w);
                am_h[mr] = v;
            } else {
                int ko = (hi4 ^ ((r >> 1) & 3)) * 8;
                am_h[mr] = *(const short8v*)&As_h[b][r * 32 + ko];
            }
        }
#pragma unroll
        for (int ncc = 0; ncc < 8; ncc += 4) {   // split B loads: cap VGPR
            short8v bn_h[4];
#pragma unroll
            for (int j = 0; j < 4; j++) {
                int n = (ncc + j) * 16 + lr;
                int ko = (hi4 ^ ((n >> 1) & 3)) * 8;
                bn_h[j] = *(const short8v*)&Bs_h[b][n * 32 + ko];
            }
#pragma unroll
            for (int mr = 0; mr < 2; mr++)
#pragma unroll
                for (int j = 0; j < 4; j++)
                    acc[mr][ncc + j] = mfma16(am_h[mr], bn_h[j], acc[mr][ncc + j]);
        }
        __syncthreads();  // drains next-buf loads + protects buffer swap
    }

    if constexpr (EPI == 0) {
        unsigned short* OH = half ? oh1 : oh0;
        const float* v1 = half ? at2 : ah2;
        const float* v2 = half ? at3 : ah3;
#pragma unroll
        for (int mr = 0; mr < 2; mr++)
#pragma unroll
            for (int rr = 0; rr < 4; rr++) {
                int row = row0 + w * 32 + mr * 16 + hi4 * 4 + rr;
                float d0 = 0.f, d1 = 0.f, d2 = 0.f;
#pragma unroll
                for (int nc = 0; nc < 8; nc++) {
                    float v = fmaxf(acc[mr][nc][rr], 0.f);
                    int col = nc * 16 + lr;
                    d0 = fmaf(v, v1[col], d0);
                    d1 = fmaf(v, v2[col], d1);
                    d2 = half ? fmaf(v, v, d2) : fmaf(v, ah4[col], d2);
                }
#pragma unroll
                for (int o = 1; o <= 8; o <<= 1) {   // reduce within 16-lane group
                    d0 += __shfl_xor(d0, o, 64);
                    d1 += __shfl_xor(d1, o, 64);
                    d2 += __shfl_xor(d2, o, 64);
                }
                float inv = 1.f;
                if (half) inv = 1.f / fmaxf(sqrtf(d2), 1e-12f);
#pragma unroll
                for (int nc = 0; nc < 8; nc++) {
                    float v = fmaxf(acc[mr][nc][rr], 0.f);
                    OH[(size_t)row * 128 + nc * 16 + lr] = f2bu(half ? v * inv : v);
                }
                if (lr == 0) {
                    if (half == 0) {
                        hb[row] = d0 + 0.25f * d1;
                        eh4o[row] = d2;
                    } else {
                        float tav = (d0 + 0.25f * d1) * inv;
                        pta[row] = make_float2(tav, __int_as_float(tidxg[row]));
                    }
                }
            }
    } else {
#pragma unroll
        for (int mr = 0; mr < 2; mr++)
#pragma unroll
            for (int rr = 0; rr < 4; rr++) {
                int row = row0 + w * 32 + mr * 16 + hi4 * 4 + rr;
                bool touched = (m3f[row] != 0u);
#pragma unroll
                for (int nc = 0; nc < 8; nc++) {
                    int col = nc * 16 + lr;
                    float a = acc[mr][nc][rr] + bias[col];
                    float g = 1.f / (1.f + expf(-a));
                    size_t o = (size_t)row * 128 + col;
                    float af = bu2f(Ah[o]);
                    float xv = 0.f;
                    if (touched) xv = xeh[o];
                    o0[o] = g * xv + (1.f - g) * af;
                }
            }
    }
}

__global__ __launch_bounds__(256) void k_mm_proj(
    const float* Af32, const unsigned short* Bh,
    unsigned short* oh0, unsigned short* oh1, int M,
    const float* ah2, const float* ah3, const float* ah4,
    const float* at2, const float* at3,
    float* hb, float* eh4o, float2* pta, const int* tidxg) {
    mm_body<0>(Af32, nullptr, Bh, oh0, oh1, nullptr, nullptr, nullptr, nullptr,
               M, ah2, ah3, ah4, at2, at3, hb, eh4o, pta, tidxg);
}

__global__ __launch_bounds__(256) void k_mm_hw(
    const unsigned short* Ah, const unsigned short* Bh,
    float* o0, const float* bias, const float* xeh, const unsigned* m3f, int M) {
    mm_body<1>(nullptr, Ah, Bh, nullptr, nullptr, o0, bias, xeh, m3f, M,
               nullptr, nullptr, nullptr, nullptr, nullptr,
               nullptr, nullptr, nullptr, nullptr);
}

// ---- counting sort by class_index ----
__global__ __launch_bounds__(256) void k_hist(const int* __restrict__ cidx,
                                              int* __restrict__ cnt, int E) {
    int i = blockIdx.x * 256 + threadIdx.x;
    if (i >= E) return;
    atomicAdd(&cnt[cidx[i]], 1);
}

__global__ __launch_bounds__(1024) void k_scan(const int* __restrict__ cnt,
                                               int* __restrict__ off,
                                               int* __restrict__ cur, int NC) {
    __shared__ int wt[16];
    __shared__ int sbase;
    int tid = threadIdx.x, w = tid >> 6, lane = tid & 63;
    if (tid == 0) sbase = 0;
    __syncthreads();
    for (int c0 = 0; c0 < NC; c0 += 1024) {
        int c = c0 + tid;
        int v = (c < NC) ? cnt[c] : 0;
        int x = v;
#pragma unroll
        for (int o = 1; o < 64; o <<= 1) {
            int t = __shfl_up(x, o, 64);
            if (lane >= o) x += t;
        }
        if (lane == 63) wt[w] = x;
        __syncthreads();
        int pre = 0, tot = 0;
#pragma unroll
        for (int i = 0; i < 16; i++) {
            int t = wt[i];
            tot += t;
            if (i < w) pre += t;
        }
        int excl = sbase + pre + x - v;
        if (c < NC) { off[c] = excl; cur[c] = excl; }
        __syncthreads();
        if (tid == 0) sbase += tot;
        __syncthreads();
    }
}

// ---- fused level-2 logit + scatter (packed 8B gather + packed 8B write) ----
__global__ __launch_bounds__(256) void k_edgescatter(
    const int* __restrict__ cidx, int* __restrict__ cur,
    const int* __restrict__ hidx, const int* __restrict__ tidx,
    const int* __restrict__ rel, const float2* __restrict__ pta,
    const float* __restrict__ hb, const float* __restrict__ er2,
    float2* __restrict__ e2gs, int E) {
    int i = blockIdx.x * 256 + threadIdx.x;
    if (i >= E) return;
    int pos = atomicAdd(&cur[cidx[i]], 1);
    float2 p = pta[tidx[i]];
    float z2 = p.x + hb[hidx[i]] + 0.5f * er2[rel[i]];
    e2gs[pos] = make_float2(LRELU(z2), p.y);
}

// ---- fused level-2 softmax + spmm + class-dot, one wave/class ----
__global__ __launch_bounds__(256) void k_spmm2(
    const int* __restrict__ off, const int* __restrict__ cnt,
    const float2* __restrict__ e2gs, const unsigned* __restrict__ xrtn_b,
    float* __restrict__ xclass, const float* __restrict__ ac,
    const float* __restrict__ eh4, const int* __restrict__ hclass,
    float* __restrict__ zc, unsigned* __restrict__ m3, int NC) {
    int lane = threadIdx.x & 63;
    int c = blockIdx.x * 4 + (threadIdx.x >> 6);
    if (c >= NC) return;
    int n = cnt[c];
    float a0 = 0.f, a1 = 0.f;
    if (n > 0) {
        int base = off[c];
        float m = -3.4e38f, s = 0.f;
        for (int j = lane; j < n; j += 64) {
            float z = e2gs[base + j].x;
            if (z > m) { s = s * __expf(m - z) + 1.f; m = z; }
            else s += __expf(z - m);
        }
        float M = wredmax(m);
        s = wred(s * __expf(m - M));
        float inv = 1.f / (s + 1e-16f);
        for (int j0 = 0; j0 < n; j0 += 64) {
            int lim = n - j0;
            if (lim > 64) lim = 64;
            float wv = 0.f;
            int g = 0;
            if (lane < lim) {
                float2 pg = e2gs[base + j0 + lane];
                wv = __expf(pg.x - M) * inv;
                g = __float_as_int(pg.y);
            }
            int jj = 0;
            for (; jj + 8 <= lim; jj += 8) {  // 8 rows in flight, 256B each
                float w0 = __shfl(wv, jj + 0), w1 = __shfl(wv, jj + 1);
                float w2 = __shfl(wv, jj + 2), w3 = __shfl(wv, jj + 3);
                float w4 = __shfl(wv, jj + 4), w5 = __shfl(wv, jj + 5);
                float w6 = __shfl(wv, jj + 6), w7 = __shfl(wv, jj + 7);
                unsigned u0 = xrtn_b[(size_t)__shfl(g, jj + 0) * 64 + lane];
                unsigned u1 = xrtn_b[(size_t)__shfl(g, jj + 1) * 64 + lane];
                unsigned u2 = xrtn_b[(size_t)__shfl(g, jj + 2) * 64 + lane];
                unsigned u3 = xrtn_b[(size_t)__shfl(g, jj + 3) * 64 + lane];
                unsigned u4 = xrtn_b[(size_t)__shfl(g, jj + 4) * 64 + lane];
                unsigned u5 = xrtn_b[(size_t)__shfl(g, jj + 5) * 64 + lane];
                unsigned u6 = xrtn_b[(size_t)__shfl(g, jj + 6) * 64 + lane];
                unsigned u7 = xrtn_b[(size_t)__shfl(g, jj + 7) * 64 + lane];
                a0 = fmaf(w0, bu2f((unsigned short)(u0 & 0xffff)), a0);
                a1 = fmaf(w0, bu2f((unsigned short)(u0 >> 16)), a1);
                a0 = fmaf(w1, bu2f((unsigned short)(u1 & 0xffff)), a0);
                a1 = fmaf(w1, bu2f((unsigned short)(u1 >> 16)), a1);
                a0 = fmaf(w2, bu2f((unsigned short)(u2 & 0xffff)), a0);
                a1 = fmaf(w2, bu2f((unsigned short)(u2 >> 16)), a1);
                a0 = fmaf(w3, bu2f((unsigned short)(u3 & 0xffff)), a0);
                a1 = fmaf(w3, bu2f((unsigned short)(u3 >> 16)), a1);
                a0 = fmaf(w4, bu2f((unsigned short)(u4 & 0xffff)), a0);
                a1 = fmaf(w4, bu2f((unsigned short)(u4 >> 16)), a1);
                a0 = fmaf(w5, bu2f((unsigned short)(u5 & 0xffff)), a0);
                a1 = fmaf(w5, bu2f((unsigned short)(u5 >> 16)), a1);
                a0 = fmaf(w6, bu2f((unsigned short)(u6 & 0xffff)), a0);
                a1 = fmaf(w6, bu2f((unsigned short)(u6 >> 16)), a1);
                a0 = fmaf(w7, bu2f((unsigned short)(u7 & 0xffff)), a0);
                a1 = fmaf(w7, bu2f((unsigned short)(u7 >> 16)), a1);
            }
            for (; jj < lim; jj++) {
                float wj = __shfl(wv, jj);
                unsigned u = xrtn_b[(size_t)__shfl(g, jj) * 64 + lane];
                a0 = fmaf(wj, bu2f((unsigned short)(u & 0xffff)), a0);
                a1 = fmaf(wj, bu2f((unsigned short)(u >> 16)), a1);
            }
        }
    }
    *(float2*)&xclass[(size_t)c * 128 + 2 * lane] = make_float2(a0, a1);
    float p = wred(a0 * ac[2 * lane] + a1 * ac[2 * lane + 1]);
    if (lane == 0) {
        int hc = hclass[c];
        float z = LRELU(p + eh4[hc]);
        zc[c] = z;
        atomicMax(&m3[hc], fenc(z));
    }
}

// ---- level 3: class -> head entity ----
__global__ __launch_bounds__(256) void k_class2(
    const int* __restrict__ hclass, float* __restrict__ zc,
    const unsigned* __restrict__ m3, float* __restrict__ s3,
    float* __restrict__ xeh, int NC) {
    int lane = threadIdx.x & 63;
    int c = blockIdx.x * 4 + (threadIdx.x >> 6);
    if (c >= NC) return;
    int hc = hclass[c];
    *(float2*)&xeh[(size_t)hc * 128 + 2 * lane] = make_float2(0.f, 0.f);
    if (lane == 0) {
        float ex = expf(zc[c] - fdec(m3[hc]));
        zc[c] = ex;
        atomicAdd(&s3[hc], ex);
    }
}

__global__ __launch_bounds__(256) void k_class3(
    const int* __restrict__ hclass, const float* __restrict__ zc,
    const float* __restrict__ s3, const float* __restrict__ xclass,
    float* __restrict__ xeh, int NC) {
    int lane = threadIdx.x & 63;
    int c = blockIdx.x * 4 + (threadIdx.x >> 6);
    if (c >= NC) return;
    int hc = hclass[c];
    float gama = zc[c] / (s3[hc] + 1e-16f);
    float v0 = xclass[(size_t)c * 128 + lane], v1 = xclass[(size_t)c * 128 + 64 + lane];
    atomicAdd(&xeh[(size_t)hc * 128 + lane], gama * v0);
    atomicAdd(&xeh[(size_t)hc * 128 + 64 + lane], gama * v1);
}

extern "C" void kernel_launch(void* const* d_in, const int* in_sizes, int n_in,
                              void* d_out, int out_size, void* d_ws, size_t ws_size,
                              hipStream_t stream) {
    (void)n_in; (void)out_size; (void)ws_size;
    const float* xe   = (const float*)d_in[0];
    const int*   eidx = (const int*)d_in[1];
    const int*   rel  = (const int*)d_in[2];
    const float* remb = (const float*)d_in[4];
    const int*   cidx = (const int*)d_in[5];
    const int*   hcls = (const int*)d_in[6];
    const float* ah2  = (const float*)d_in[8];
    const float* ah3  = (const float*)d_in[9];
    const float* ah4  = (const float*)d_in[10];
    const float* at2  = (const float*)d_in[12];
    const float* at3  = (const float*)d_in[13];
    const float* ar2  = (const float*)d_in[15];
    const float* ac   = (const float*)d_in[16];
    const float* wh   = (const float*)d_in[17];
    const float* wt   = (const float*)d_in[18];
    const float* hww  = (const float*)d_in[19];
    const float* hwb  = (const float*)d_in[20];
    float* out = (float*)d_out;

    const int NE = in_sizes[0] / 256;
    const int E  = in_sizes[2];
    const int NR = in_sizes[4] / 128;
    const int NC = in_sizes[6];
    const int* hidx = eidx;
    const int* tidx = eidx + E;

    char* base = (char*)d_ws;
    size_t off0 = 0;
    auto alloc = [&](size_t bytes) -> char* {
        char* r = base + off0;
        off0 = (off0 + bytes + 255) & ~(size_t)255;
        return r;
    };
    float* hb   = (float*)alloc((size_t)NE * 4);
    float* eh4b = (float*)alloc((size_t)NE * 4);
    float2* pta = (float2*)alloc((size_t)NE * 8);
    float* er2b = (float*)alloc((size_t)NR * 4);
    float2* e2gs = (float2*)alloc((size_t)E * 8);
    float* zc   = (float*)alloc((size_t)NC * 4);
    unsigned short* wtb_hi = (unsigned short*)alloc((size_t)256 * 256 * 2);
    unsigned short* hwt_hi = (unsigned short*)alloc((size_t)128 * 128 * 2);
    unsigned short* xrh_hi = (unsigned short*)alloc((size_t)NE * 128 * 2);
    unsigned short* xrtn   = (unsigned short*)alloc((size_t)NE * 128 * 2);
    int* offb = (int*)alloc((size_t)NC * 4);
    int* curb = (int*)alloc((size_t)NC * 4);
    float* xclass = (float*)alloc((size_t)NC * 128 * 4);
    float* xeh    = (float*)alloc((size_t)NE * 128 * 4);  // zeroed per-launch by
    // k_class2 for touched hc only; untouched rows never read (m3 guard).
    size_t zoff = off0;  // everything below is zero-initialized per launch
    unsigned* m3 = (unsigned*)alloc((size_t)NE * 4);
    float* s3    = (float*)alloc((size_t)NE * 4);
    int* cntb    = (int*)alloc((size_t)NC * 4);
    size_t zbytes = off0 - zoff;

    hipMemsetAsync(base + zoff, 0, zbytes, stream);

    k_convW<<<(256 * 256 + 128 * 128 + 255) / 256, 256, 0, stream>>>(
        wh, wt, hww, wtb_hi, hwt_hi);
    k_rel<<<(NR + 3) / 4, 256, 0, stream>>>(remb, ar2, er2b, NR);

    // projection GEMM: async f32 A staging (16B-slot swizzle, conflict-free),
    // bf16 mirrors (xrt pre-normalized) + fused dots + packed pta records
    k_mm_proj<<<((NE + 127) / 128) * 2, 256, 0, stream>>>(
        xe, wtb_hi, xrh_hi, xrtn, NE,
        ah2, ah3, ah4, at2, at3, hb, eh4b, pta, tidx);

    // class-CSR histogram/scan
    k_hist<<<(E + 255) / 256, 256, 0, stream>>>(cidx, cntb, E);
    k_scan<<<1, 1024, 0, stream>>>(cntb, offb, curb, NC);

    // fused level-2 logit + scatter (level-1 softmax cancels vs F.normalize)
    k_edgescatter<<<(E + 255) / 256, 256, 0, stream>>>(
        cidx, curb, hidx, tidx, rel, pta, hb, er2b, e2gs, E);

    k_spmm2<<<(NC + 3) / 4, 256, 0, stream>>>(offb, cntb, e2gs,
                                              (const unsigned*)xrtn, xclass,
                                              ac, eh4b, hcls, zc, m3, NC);
    k_class2<<<(NC + 3) / 4, 256, 0, stream>>>(hcls, zc, m3, s3, xeh, NC);
    k_class3<<<(NC + 3) / 4, 256, 0, stream>>>(hcls, zc, s3, xclass, xeh, NC);

    k_mm_hw<<<(NE + 127) / 128, 256, 0, stream>>>(
        xrh_hi, hwt_hi, out, hwb, xeh, m3, NE);
}

// Round 20
// 276.117 us; speedup vs baseline: 1.0485x; 1.0225x over previous
//
#include <hip/hip_runtime.h>
#include <hip/hip_bf16.h>

#define LRELU(x) ((x) >= 0.f ? (x) : 0.01f * (x))

typedef __attribute__((ext_vector_type(8))) short short8v;
typedef __attribute__((ext_vector_type(4))) float f32x4;

__device__ inline unsigned fenc(float x) {
    unsigned u = __float_as_uint(x);
    return (u & 0x80000000u) ? ~u : (u | 0x80000000u);
}
__device__ inline float fdec(unsigned e) {
    return __uint_as_float((e & 0x80000000u) ? (e ^ 0x80000000u) : ~e);
}

__device__ inline float wred(float v) {
#pragma unroll
    for (int o = 32; o > 0; o >>= 1) v += __shfl_xor(v, o, 64);
    return v;
}
__device__ inline float wredmax(float v) {
#pragma unroll
    for (int o = 32; o > 0; o >>= 1) v = fmaxf(v, __shfl_xor(v, o, 64));
    return v;
}

__device__ inline unsigned short f2bu(float x) {
    __hip_bfloat16 b = __float2bfloat16(x);
    return *reinterpret_cast<unsigned short*>(&b);
}
__device__ inline float bu2f(unsigned short u) {
    return __uint_as_float((unsigned)u << 16);
}

__device__ inline f32x4 mfma16(short8v a, short8v b, f32x4 c) {
    return __builtin_amdgcn_mfma_f32_16x16x32_bf16(a, b, c, 0, 0, 0);
}

// async global->LDS, 16B per lane, dest = (wave-uniform base) + lane*16
__device__ inline void gload16(const void* g, void* l) {
    __builtin_amdgcn_global_load_lds(
        (const __attribute__((address_space(1))) void*)g,
        (__attribute__((address_space(3))) void*)l, 16, 0, 0);
}

// ---- convert W matrices to transposed bf16: Wt[n][k] = bf16(W[k][n]) ----
__global__ __launch_bounds__(256) void k_convW(
    const float* __restrict__ wh, const float* __restrict__ wt,
    const float* __restrict__ hww, unsigned short* __restrict__ wtb_hi,
    unsigned short* __restrict__ hwt_hi) {
    int id = blockIdx.x * 256 + threadIdx.x;
    if (id < 256 * 256) {
        int n = id >> 8, k = id & 255;
        float v = (n < 128) ? wh[(size_t)k * 128 + n] : wt[(size_t)k * 128 + (n - 128)];
        wtb_hi[(size_t)n * 256 + k] = f2bu(v);
    } else {
        int id2 = id - 256 * 256;
        if (id2 < 128 * 128) {
            int n = id2 >> 7, k = id2 & 127;
            hwt_hi[(size_t)n * 128 + k] = f2bu(hww[(size_t)k * 128 + n]);
        }
    }
}

// ---- relation dot: er2[r] = r_emb[r]·a_r2 ----
__global__ __launch_bounds__(256) void k_rel(const float* __restrict__ remb,
                                             const float* __restrict__ ar2,
                                             float* __restrict__ er2, int NR) {
    int lane = threadIdx.x & 63;
    int r = blockIdx.x * 4 + (threadIdx.x >> 6);
    if (r >= NR) return;
    float v0 = remb[(size_t)r * 128 + lane];
    float v1 = remb[(size_t)r * 128 + 64 + lane];
    float p2 = wred(v0 * ar2[lane] + v1 * ar2[64 + lane]);
    if (lane == 0) er2[r] = p2;
}

// ---- projection GEMM: 8-wave block, both col-halves in one pass ----
// Block 128 rows x 256 cols (wh||wt), 8 waves: wave w = rowgroup (w&3) x
// col-half (w>>2); acc[2][8]/wave; 2-phase double-buffered LDS; A staged as
// f32 (16B-slot involutive swizzle, conflict-free), cvt->bf16 at read.
// A tile loaded ONCE per block (was twice). One barrier/step.
// half0 -> oh0=bf16(relu(xe@wh)), hb, eh4o;
// half1 -> oh1=bf16(relu(xe@wt)*inv) pre-normalized, pta={ta, tidx[row]}.
__global__ __launch_bounds__(512) void k_mm_proj(
    const float* __restrict__ Af32, const unsigned short* __restrict__ Bh,
    unsigned short* __restrict__ oh0, unsigned short* __restrict__ oh1, int M,
    const float* __restrict__ ah2, const float* __restrict__ ah3,
    const float* __restrict__ ah4, const float* __restrict__ at2,
    const float* __restrict__ at3,
    float* __restrict__ hb, float* __restrict__ eh4o,
    float2* __restrict__ pta, const int* __restrict__ tidxg) {
    constexpr int KD = 256;
    constexpr int NSTEP = KD / 32;
    __shared__ float As_f[2][128 * 32];
    __shared__ unsigned short Bs_h[2][256 * 32];

    int row0 = blockIdx.x * 128;
    if (row0 + 128 > M) row0 = M - 128;
    int tid = threadIdx.x, w = tid >> 6, l = tid & 63;
    int rg = w & 3, ch = w >> 2;
    int lr = l & 15, hi4 = l >> 4;
    int srow = l >> 2, sslot = l & 3;      // bf16 unit: 16 rows, 4x16B/row
    int arow = l >> 3, afi = l & 7;        // f32 unit: 8 rows, 8x16B/row

    f32x4 acc[2][8];
#pragma unroll
    for (int i = 0; i < 2; i++)
#pragma unroll
        for (int j = 0; j < 8; j++) acc[i][j] = (f32x4){0.f, 0.f, 0.f, 0.f};

    auto stage = [&](int s, int b) {
        int k0 = s * 32;
#pragma unroll
        for (int i = 0; i < 4; i++) {          // 32 units, 4/wave
            int u = w * 4 + i;
            if (u < 16) {  // A f32 unit: 1KB, 8 rows x 8 16B-slots
                int row = u * 8 + arow;
                int sf = ((afi ^ arow) << 2);  // 16B-slot involutive swizzle
                gload16(Af32 + (size_t)(row0 + row) * KD + k0 + sf,
                        (char*)&As_f[b][0] + u * 1024);
            } else {       // B bf16 unit: 1KB, 16 n-rows of 64B
                int ub = u - 16;
                int n = ub * 16 + srow;        // n in [0,256): wh||wt cols
                int klog = (sslot ^ ((n >> 1) & 3)) * 8;
                gload16(Bh + (size_t)n * KD + k0 + klog,
                        (char*)&Bs_h[b][0] + ub * 1024);
            }
        }
    };

    stage(0, 0);
    __syncthreads();                              // buf0 ready
    for (int s = 0; s < NSTEP; s++) {
        int b = s & 1;
        if (s + 1 < NSTEP) stage(s + 1, b ^ 1);  // all loads fly under compute

        short8v am_h[2];
#pragma unroll
        for (int mr = 0; mr < 2; mr++) {
            int r = rg * 32 + mr * 16 + lr;
            int s0 = ((2 * hi4 + 0) ^ (r & 7)) * 4;
            int s1 = ((2 * hi4 + 1) ^ (r & 7)) * 4;
            float4 f0 = *(const float4*)&As_f[b][r * 32 + s0];
            float4 f1 = *(const float4*)&As_f[b][r * 32 + s1];
            short8v v;
            v[0] = (short)f2bu(f0.x); v[1] = (short)f2bu(f0.y);
            v[2] = (short)f2bu(f0.z); v[3] = (short)f2bu(f0.w);
            v[4] = (short)f2bu(f1.x); v[5] = (short)f2bu(f1.y);
            v[6] = (short)f2bu(f1.z); v[7] = (short)f2bu(f1.w);
            am_h[mr] = v;
        }
#pragma unroll
        for (int ncc = 0; ncc < 8; ncc += 4) {   // split B loads: cap VGPR
            short8v bn_h[4];
#pragma unroll
            for (int j = 0; j < 4; j++) {
                int n = ch * 128 + (ncc + j) * 16 + lr;
                int ko = (hi4 ^ ((n >> 1) & 3)) * 8;
                bn_h[j] = *(const short8v*)&Bs_h[b][n * 32 + ko];
            }
#pragma unroll
            for (int mr = 0; mr < 2; mr++)
#pragma unroll
                for (int j = 0; j < 4; j++)
                    acc[mr][ncc + j] = mfma16(am_h[mr], bn_h[j], acc[mr][ncc + j]);
        }
        __syncthreads();  // drains next-buf loads + protects buffer swap
    }

    unsigned short* OH = ch ? oh1 : oh0;
    const float* v1 = ch ? at2 : ah2;
    const float* v2 = ch ? at3 : ah3;
#pragma unroll
    for (int mr = 0; mr < 2; mr++)
#pragma unroll
        for (int rr = 0; rr < 4; rr++) {
            int row = row0 + rg * 32 + mr * 16 + hi4 * 4 + rr;
            float d0 = 0.f, d1 = 0.f, d2 = 0.f;
#pragma unroll
            for (int nc = 0; nc < 8; nc++) {
                float v = fmaxf(acc[mr][nc][rr], 0.f);
                int col = nc * 16 + lr;
                d0 = fmaf(v, v1[col], d0);
                d1 = fmaf(v, v2[col], d1);
                d2 = ch ? fmaf(v, v, d2) : fmaf(v, ah4[col], d2);
            }
#pragma unroll
            for (int o = 1; o <= 8; o <<= 1) {   // reduce within 16-lane group
                d0 += __shfl_xor(d0, o, 64);
                d1 += __shfl_xor(d1, o, 64);
                d2 += __shfl_xor(d2, o, 64);
            }
            float inv = 1.f;
            if (ch) inv = 1.f / fmaxf(sqrtf(d2), 1e-12f);
#pragma unroll
            for (int nc = 0; nc < 8; nc++) {
                float v = fmaxf(acc[mr][nc][rr], 0.f);
                OH[(size_t)row * 128 + nc * 16 + lr] = f2bu(ch ? v * inv : v);
            }
            if (lr == 0) {
                if (ch == 0) {
                    hb[row] = d0 + 0.25f * d1;
                    eh4o[row] = d2;
                } else {
                    float tav = (d0 + 0.25f * d1) * inv;
                    pta[row] = make_float2(tav, __int_as_float(tidxg[row]));
                }
            }
        }
}

// ---- highway GEMM (KD=128, A bf16): 4-wave 128x128 block ----
// gate=sigmoid(C+bias); o0 = g*(m3[row]?xeh:0) + (1-g)*bf16(A).
__global__ __launch_bounds__(256) void k_mm_hw(
    const unsigned short* __restrict__ Ah, const unsigned short* __restrict__ Bh,
    float* __restrict__ o0, const float* __restrict__ bias,
    const float* __restrict__ xeh, const unsigned* __restrict__ m3f, int M) {
    constexpr int KD = 128;
    constexpr int NSTEP = KD / 32;
    __shared__ unsigned short As_h[2][128 * 32];
    __shared__ unsigned short Bs_h[2][128 * 32];

    int row0 = blockIdx.x * 128;
    if (row0 + 128 > M) row0 = M - 128;
    int tid = threadIdx.x, w = tid >> 6, l = tid & 63;
    int lr = l & 15, hi4 = l >> 4;
    int srow = l >> 2, sslot = l & 3;

    f32x4 acc[2][8];
#pragma unroll
    for (int i = 0; i < 2; i++)
#pragma unroll
        for (int j = 0; j < 8; j++) acc[i][j] = (f32x4){0.f, 0.f, 0.f, 0.f};

    auto stage = [&](int s, int b) {
        int k0 = s * 32;
#pragma unroll
        for (int i = 0; i < 4; i++) {
            int u = w * 4 + i;
            int arr = u >> 3, ld = u & 7;
            int row = ld * 16 + srow;
            int klog = (sslot ^ ((row >> 1) & 3)) * 8;
            if (arr == 0)
                gload16(Ah + (size_t)(row0 + row) * KD + k0 + klog,
                        (char*)&As_h[b][0] + ld * 1024);
            else
                gload16(Bh + (size_t)row * KD + k0 + klog,
                        (char*)&Bs_h[b][0] + ld * 1024);
        }
    };

    stage(0, 0);
    __syncthreads();
    for (int s = 0; s < NSTEP; s++) {
        int b = s & 1;
        if (s + 1 < NSTEP) stage(s + 1, b ^ 1);
        short8v am_h[2];
#pragma unroll
        for (int mr = 0; mr < 2; mr++) {
            int r = w * 32 + mr * 16 + lr;
            int ko = (hi4 ^ ((r >> 1) & 3)) * 8;
            am_h[mr] = *(const short8v*)&As_h[b][r * 32 + ko];
        }
#pragma unroll
        for (int ncc = 0; ncc < 8; ncc += 4) {
            short8v bn_h[4];
#pragma unroll
            for (int j = 0; j < 4; j++) {
                int n = (ncc + j) * 16 + lr;
                int ko = (hi4 ^ ((n >> 1) & 3)) * 8;
                bn_h[j] = *(const short8v*)&Bs_h[b][n * 32 + ko];
            }
#pragma unroll
            for (int mr = 0; mr < 2; mr++)
#pragma unroll
                for (int j = 0; j < 4; j++)
                    acc[mr][ncc + j] = mfma16(am_h[mr], bn_h[j], acc[mr][ncc + j]);
        }
        __syncthreads();
    }

#pragma unroll
    for (int mr = 0; mr < 2; mr++)
#pragma unroll
        for (int rr = 0; rr < 4; rr++) {
            int row = row0 + w * 32 + mr * 16 + hi4 * 4 + rr;
            bool touched = (m3f[row] != 0u);
#pragma unroll
            for (int nc = 0; nc < 8; nc++) {
                int col = nc * 16 + lr;
                float a = acc[mr][nc][rr] + bias[col];
                float g = 1.f / (1.f + expf(-a));
                size_t o = (size_t)row * 128 + col;
                float af = bu2f(Ah[o]);
                float xv = 0.f;
                if (touched) xv = xeh[o];
                o0[o] = g * xv + (1.f - g) * af;
            }
        }
}

// ---- counting sort by class_index ----
__global__ __launch_bounds__(256) void k_hist(const int* __restrict__ cidx,
                                              int* __restrict__ cnt, int E) {
    int i = blockIdx.x * 256 + threadIdx.x;
    if (i >= E) return;
    atomicAdd(&cnt[cidx[i]], 1);
}

__global__ __launch_bounds__(1024) void k_scan(const int* __restrict__ cnt,
                                               int* __restrict__ off,
                                               int* __restrict__ cur, int NC) {
    __shared__ int wt[16];
    __shared__ int sbase;
    int tid = threadIdx.x, w = tid >> 6, lane = tid & 63;
    if (tid == 0) sbase = 0;
    __syncthreads();
    for (int c0 = 0; c0 < NC; c0 += 1024) {
        int c = c0 + tid;
        int v = (c < NC) ? cnt[c] : 0;
        int x = v;
#pragma unroll
        for (int o = 1; o < 64; o <<= 1) {
            int t = __shfl_up(x, o, 64);
            if (lane >= o) x += t;
        }
        if (lane == 63) wt[w] = x;
        __syncthreads();
        int pre = 0, tot = 0;
#pragma unroll
        for (int i = 0; i < 16; i++) {
            int t = wt[i];
            tot += t;
            if (i < w) pre += t;
        }
        int excl = sbase + pre + x - v;
        if (c < NC) { off[c] = excl; cur[c] = excl; }
        __syncthreads();
        if (tid == 0) sbase += tot;
        __syncthreads();
    }
}

// ---- fused level-2 logit + scatter (packed 8B gather + packed 8B write) ----
__global__ __launch_bounds__(256) void k_edgescatter(
    const int* __restrict__ cidx, int* __restrict__ cur,
    const int* __restrict__ hidx, const int* __restrict__ tidx,
    const int* __restrict__ rel, const float2* __restrict__ pta,
    const float* __restrict__ hb, const float* __restrict__ er2,
    float2* __restrict__ e2gs, int E) {
    int i = blockIdx.x * 256 + threadIdx.x;
    if (i >= E) return;
    int pos = atomicAdd(&cur[cidx[i]], 1);
    float2 p = pta[tidx[i]];
    float z2 = p.x + hb[hidx[i]] + 0.5f * er2[rel[i]];
    e2gs[pos] = make_float2(LRELU(z2), p.y);
}

// ---- fused level-2 softmax + spmm + class-dot, one wave/class ----
__global__ __launch_bounds__(256) void k_spmm2(
    const int* __restrict__ off, const int* __restrict__ cnt,
    const float2* __restrict__ e2gs, const unsigned* __restrict__ xrtn_b,
    float* __restrict__ xclass, const float* __restrict__ ac,
    const float* __restrict__ eh4, const int* __restrict__ hclass,
    float* __restrict__ zc, unsigned* __restrict__ m3, int NC) {
    int lane = threadIdx.x & 63;
    int c = blockIdx.x * 4 + (threadIdx.x >> 6);
    if (c >= NC) return;
    int n = cnt[c];
    float a0 = 0.f, a1 = 0.f;
    if (n > 0) {
        int base = off[c];
        float m = -3.4e38f, s = 0.f;
        for (int j = lane; j < n; j += 64) {
            float z = e2gs[base + j].x;
            if (z > m) { s = s * __expf(m - z) + 1.f; m = z; }
            else s += __expf(z - m);
        }
        float M = wredmax(m);
        s = wred(s * __expf(m - M));
        float inv = 1.f / (s + 1e-16f);
        for (int j0 = 0; j0 < n; j0 += 64) {
            int lim = n - j0;
            if (lim > 64) lim = 64;
            float wv = 0.f;
            int g = 0;
            if (lane < lim) {
                float2 pg = e2gs[base + j0 + lane];
                wv = __expf(pg.x - M) * inv;
                g = __float_as_int(pg.y);
            }
            int jj = 0;
            for (; jj + 8 <= lim; jj += 8) {  // 8 rows in flight, 256B each
                float w0 = __shfl(wv, jj + 0), w1 = __shfl(wv, jj + 1);
                float w2 = __shfl(wv, jj + 2), w3 = __shfl(wv, jj + 3);
                float w4 = __shfl(wv, jj + 4), w5 = __shfl(wv, jj + 5);
                float w6 = __shfl(wv, jj + 6), w7 = __shfl(wv, jj + 7);
                unsigned u0 = xrtn_b[(size_t)__shfl(g, jj + 0) * 64 + lane];
                unsigned u1 = xrtn_b[(size_t)__shfl(g, jj + 1) * 64 + lane];
                unsigned u2 = xrtn_b[(size_t)__shfl(g, jj + 2) * 64 + lane];
                unsigned u3 = xrtn_b[(size_t)__shfl(g, jj + 3) * 64 + lane];
                unsigned u4 = xrtn_b[(size_t)__shfl(g, jj + 4) * 64 + lane];
                unsigned u5 = xrtn_b[(size_t)__shfl(g, jj + 5) * 64 + lane];
                unsigned u6 = xrtn_b[(size_t)__shfl(g, jj + 6) * 64 + lane];
                unsigned u7 = xrtn_b[(size_t)__shfl(g, jj + 7) * 64 + lane];
                a0 = fmaf(w0, bu2f((unsigned short)(u0 & 0xffff)), a0);
                a1 = fmaf(w0, bu2f((unsigned short)(u0 >> 16)), a1);
                a0 = fmaf(w1, bu2f((unsigned short)(u1 & 0xffff)), a0);
                a1 = fmaf(w1, bu2f((unsigned short)(u1 >> 16)), a1);
                a0 = fmaf(w2, bu2f((unsigned short)(u2 & 0xffff)), a0);
                a1 = fmaf(w2, bu2f((unsigned short)(u2 >> 16)), a1);
                a0 = fmaf(w3, bu2f((unsigned short)(u3 & 0xffff)), a0);
                a1 = fmaf(w3, bu2f((unsigned short)(u3 >> 16)), a1);
                a0 = fmaf(w4, bu2f((unsigned short)(u4 & 0xffff)), a0);
                a1 = fmaf(w4, bu2f((unsigned short)(u4 >> 16)), a1);
                a0 = fmaf(w5, bu2f((unsigned short)(u5 & 0xffff)), a0);
                a1 = fmaf(w5, bu2f((unsigned short)(u5 >> 16)), a1);
                a0 = fmaf(w6, bu2f((unsigned short)(u6 & 0xffff)), a0);
                a1 = fmaf(w6, bu2f((unsigned short)(u6 >> 16)), a1);
                a0 = fmaf(w7, bu2f((unsigned short)(u7 & 0xffff)), a0);
                a1 = fmaf(w7, bu2f((unsigned short)(u7 >> 16)), a1);
            }
            for (; jj < lim; jj++) {
                float wj = __shfl(wv, jj);
                unsigned u = xrtn_b[(size_t)__shfl(g, jj) * 64 + lane];
                a0 = fmaf(wj, bu2f((unsigned short)(u & 0xffff)), a0);
                a1 = fmaf(wj, bu2f((unsigned short)(u >> 16)), a1);
            }
        }
    }
    *(float2*)&xclass[(size_t)c * 128 + 2 * lane] = make_float2(a0, a1);
    float p = wred(a0 * ac[2 * lane] + a1 * ac[2 * lane + 1]);
    if (lane == 0) {
        int hc = hclass[c];
        float z = LRELU(p + eh4[hc]);
        zc[c] = z;
        atomicMax(&m3[hc], fenc(z));
    }
}

// ---- level 3: class -> head entity ----
__global__ __launch_bounds__(256) void k_class2(
    const int* __restrict__ hclass, float* __restrict__ zc,
    const unsigned* __restrict__ m3, float* __restrict__ s3,
    float* __restrict__ xeh, int NC) {
    int lane = threadIdx.x & 63;
    int c = blockIdx.x * 4 + (threadIdx.x >> 6);
    if (c >= NC) return;
    int hc = hclass[c];
    *(float2*)&xeh[(size_t)hc * 128 + 2 * lane] = make_float2(0.f, 0.f);
    if (lane == 0) {
        float ex = expf(zc[c] - fdec(m3[hc]));
        zc[c] = ex;
        atomicAdd(&s3[hc], ex);
    }
}

__global__ __launch_bounds__(256) void k_class3(
    const int* __restrict__ hclass, const float* __restrict__ zc,
    const float* __restrict__ s3, const float* __restrict__ xclass,
    float* __restrict__ xeh, int NC) {
    int lane = threadIdx.x & 63;
    int c = blockIdx.x * 4 + (threadIdx.x >> 6);
    if (c >= NC) return;
    int hc = hclass[c];
    float gama = zc[c] / (s3[hc] + 1e-16f);
    float v0 = xclass[(size_t)c * 128 + lane], v1 = xclass[(size_t)c * 128 + 64 + lane];
    atomicAdd(&xeh[(size_t)hc * 128 + lane], gama * v0);
    atomicAdd(&xeh[(size_t)hc * 128 + 64 + lane], gama * v1);
}

extern "C" void kernel_launch(void* const* d_in, const int* in_sizes, int n_in,
                              void* d_out, int out_size, void* d_ws, size_t ws_size,
                              hipStream_t stream) {
    (void)n_in; (void)out_size; (void)ws_size;
    const float* xe   = (const float*)d_in[0];
    const int*   eidx = (const int*)d_in[1];
    const int*   rel  = (const int*)d_in[2];
    const float* remb = (const float*)d_in[4];
    const int*   cidx = (const int*)d_in[5];
    const int*   hcls = (const int*)d_in[6];
    const float* ah2  = (const float*)d_in[8];
    const float* ah3  = (const float*)d_in[9];
    const float* ah4  = (const float*)d_in[10];
    const float* at2  = (const float*)d_in[12];
    const float* at3  = (const float*)d_in[13];
    const float* ar2  = (const float*)d_in[15];
    const float* ac   = (const float*)d_in[16];
    const float* wh   = (const float*)d_in[17];
    const float* wt   = (const float*)d_in[18];
    const float* hww  = (const float*)d_in[19];
    const float* hwb  = (const float*)d_in[20];
    float* out = (float*)d_out;

    const int NE = in_sizes[0] / 256;
    const int E  = in_sizes[2];
    const int NR = in_sizes[4] / 128;
    const int NC = in_sizes[6];
    const int* hidx = eidx;
    const int* tidx = eidx + E;

    char* base = (char*)d_ws;
    size_t off0 = 0;
    auto alloc = [&](size_t bytes) -> char* {
        char* r = base + off0;
        off0 = (off0 + bytes + 255) & ~(size_t)255;
        return r;
    };
    float* hb   = (float*)alloc((size_t)NE * 4);
    float* eh4b = (float*)alloc((size_t)NE * 4);
    float2* pta = (float2*)alloc((size_t)NE * 8);
    float* er2b = (float*)alloc((size_t)NR * 4);
    float2* e2gs = (float2*)alloc((size_t)E * 8);
    float* zc   = (float*)alloc((size_t)NC * 4);
    unsigned short* wtb_hi = (unsigned short*)alloc((size_t)256 * 256 * 2);
    unsigned short* hwt_hi = (unsigned short*)alloc((size_t)128 * 128 * 2);
    unsigned short* xrh_hi = (unsigned short*)alloc((size_t)NE * 128 * 2);
    unsigned short* xrtn   = (unsigned short*)alloc((size_t)NE * 128 * 2);
    int* offb = (int*)alloc((size_t)NC * 4);
    int* curb = (int*)alloc((size_t)NC * 4);
    float* xclass = (float*)alloc((size_t)NC * 128 * 4);
    float* xeh    = (float*)alloc((size_t)NE * 128 * 4);  // zeroed per-launch by
    // k_class2 for touched hc only; untouched rows never read (m3 guard).
    size_t zoff = off0;  // everything below is zero-initialized per launch
    unsigned* m3 = (unsigned*)alloc((size_t)NE * 4);
    float* s3    = (float*)alloc((size_t)NE * 4);
    int* cntb    = (int*)alloc((size_t)NC * 4);
    size_t zbytes = off0 - zoff;

    hipMemsetAsync(base + zoff, 0, zbytes, stream);

    k_convW<<<(256 * 256 + 128 * 128 + 255) / 256, 256, 0, stream>>>(
        wh, wt, hww, wtb_hi, hwt_hi);
    k_rel<<<(NR + 3) / 4, 256, 0, stream>>>(remb, ar2, er2b, NR);

    // projection GEMM: 8-wave block, both halves per block, A staged once
    k_mm_proj<<<(NE + 127) / 128, 512, 0, stream>>>(
        xe, wtb_hi, xrh_hi, xrtn, NE,
        ah2, ah3, ah4, at2, at3, hb, eh4b, pta, tidx);

    // class-CSR histogram/scan
    k_hist<<<(E + 255) / 256, 256, 0, stream>>>(cidx, cntb, E);
    k_scan<<<1, 1024, 0, stream>>>(cntb, offb, curb, NC);

    // fused level-2 logit + scatter (level-1 softmax cancels vs F.normalize)
    k_edgescatter<<<(E + 255) / 256, 256, 0, stream>>>(
        cidx, curb, hidx, tidx, rel, pta, hb, er2b, e2gs, E);

    k_spmm2<<<(NC + 3) / 4, 256, 0, stream>>>(offb, cntb, e2gs,
                                              (const unsigned*)xrtn, xclass,
                                              ac, eh4b, hcls, zc, m3, NC);
    k_class2<<<(NC + 3) / 4, 256, 0, stream>>>(hcls, zc, m3, s3, xeh, NC);
    k_class3<<<(NC + 3) / 4, 256, 0, stream>>>(hcls, zc, s3, xclass, xeh, NC);

    k_mm_hw<<<(NE + 127) / 128, 256, 0, stream>>>(
        xrh_hi, hwt_hi, out, hwb, xeh, m3, NE);
}

// Round 21
// 260.581 us; speedup vs baseline: 1.1110x; 1.0596x over previous
//
#include <hip/hip_runtime.h>
#include <hip/hip_bf16.h>

#define LRELU(x) ((x) >= 0.f ? (x) : 0.01f * (x))

typedef __attribute__((ext_vector_type(8))) short short8v;
typedef __attribute__((ext_vector_type(4))) float f32x4;

__device__ inline unsigned fenc(float x) {
    unsigned u = __float_as_uint(x);
    return (u & 0x80000000u) ? ~u : (u | 0x80000000u);
}
__device__ inline float fdec(unsigned e) {
    return __uint_as_float((e & 0x80000000u) ? (e ^ 0x80000000u) : ~e);
}

__device__ inline float wred(float v) {
#pragma unroll
    for (int o = 32; o > 0; o >>= 1) v += __shfl_xor(v, o, 64);
    return v;
}
__device__ inline float wredmax(float v) {
#pragma unroll
    for (int o = 32; o > 0; o >>= 1) v = fmaxf(v, __shfl_xor(v, o, 64));
    return v;
}

__device__ inline unsigned short f2bu(float x) {
    __hip_bfloat16 b = __float2bfloat16(x);
    return *reinterpret_cast<unsigned short*>(&b);
}
__device__ inline float bu2f(unsigned short u) {
    return __uint_as_float((unsigned)u << 16);
}

__device__ inline f32x4 mfma16(short8v a, short8v b, f32x4 c) {
    return __builtin_amdgcn_mfma_f32_16x16x32_bf16(a, b, c, 0, 0, 0);
}

// async global->LDS, 16B per lane, dest = (wave-uniform base) + lane*16
__device__ inline void gload16(const void* g, void* l) {
    __builtin_amdgcn_global_load_lds(
        (const __attribute__((address_space(1))) void*)g,
        (__attribute__((address_space(3))) void*)l, 16, 0, 0);
}

// ---- fused prelude: convW + rel-dot + class histogram in ONE launch ----
// blocks [0,320): Wt[n][k]=bf16(W[k][n]); [320,320+ceil(NR/4)): er2 dots;
// rest: hist over class_index.
__global__ __launch_bounds__(256) void k_prelude(
    const float* __restrict__ wh, const float* __restrict__ wt,
    const float* __restrict__ hww, unsigned short* __restrict__ wtb_hi,
    unsigned short* __restrict__ hwt_hi,
    const float* __restrict__ remb, const float* __restrict__ ar2,
    float* __restrict__ er2, int NR,
    const int* __restrict__ cidx, int* __restrict__ cnt, int E,
    int nbConv, int nbRel) {
    int bx = blockIdx.x, tid = threadIdx.x;
    if (bx < nbConv) {
        int id = bx * 256 + tid;
        if (id < 256 * 256) {
            int n = id >> 8, k = id & 255;
            float v = (n < 128) ? wh[(size_t)k * 128 + n]
                                : wt[(size_t)k * 128 + (n - 128)];
            wtb_hi[(size_t)n * 256 + k] = f2bu(v);
        } else {
            int id2 = id - 256 * 256;
            if (id2 < 128 * 128) {
                int n = id2 >> 7, k = id2 & 127;
                hwt_hi[(size_t)n * 128 + k] = f2bu(hww[(size_t)k * 128 + n]);
            }
        }
    } else if (bx < nbConv + nbRel) {
        int lane = tid & 63;
        int r = (bx - nbConv) * 4 + (tid >> 6);
        if (r >= NR) return;
        float v0 = remb[(size_t)r * 128 + lane];
        float v1 = remb[(size_t)r * 128 + 64 + lane];
        float p2 = wred(v0 * ar2[lane] + v1 * ar2[64 + lane]);
        if (lane == 0) er2[r] = p2;
    } else {
        int i = (bx - nbConv - nbRel) * 256 + tid;
        if (i >= E) return;
        atomicAdd(&cnt[cidx[i]], 1);
    }
}

// ---- projection GEMM: 8-wave block, both col-halves in one pass ----
// Block 128 rows x 256 cols (wh||wt), 8 waves: wave w = rowgroup (w&3) x
// col-half (w>>2); acc[2][8]/wave; 2-phase double-buffered LDS; A staged as
// f32 (16B-slot involutive swizzle, conflict-free), cvt->bf16 at read.
__global__ __launch_bounds__(512) void k_mm_proj(
    const float* __restrict__ Af32, const unsigned short* __restrict__ Bh,
    unsigned short* __restrict__ oh0, unsigned short* __restrict__ oh1, int M,
    const float* __restrict__ ah2, const float* __restrict__ ah3,
    const float* __restrict__ ah4, const float* __restrict__ at2,
    const float* __restrict__ at3,
    float* __restrict__ hb, float* __restrict__ eh4o,
    float2* __restrict__ pta, const int* __restrict__ tidxg) {
    constexpr int KD = 256;
    constexpr int NSTEP = KD / 32;
    __shared__ float As_f[2][128 * 32];
    __shared__ unsigned short Bs_h[2][256 * 32];

    int row0 = blockIdx.x * 128;
    if (row0 + 128 > M) row0 = M - 128;
    int tid = threadIdx.x, w = tid >> 6, l = tid & 63;
    int rg = w & 3, ch = w >> 2;
    int lr = l & 15, hi4 = l >> 4;
    int srow = l >> 2, sslot = l & 3;
    int arow = l >> 3, afi = l & 7;

    f32x4 acc[2][8];
#pragma unroll
    for (int i = 0; i < 2; i++)
#pragma unroll
        for (int j = 0; j < 8; j++) acc[i][j] = (f32x4){0.f, 0.f, 0.f, 0.f};

    auto stage = [&](int s, int b) {
        int k0 = s * 32;
#pragma unroll
        for (int i = 0; i < 4; i++) {
            int u = w * 4 + i;
            if (u < 16) {
                int row = u * 8 + arow;
                int sf = ((afi ^ arow) << 2);
                gload16(Af32 + (size_t)(row0 + row) * KD + k0 + sf,
                        (char*)&As_f[b][0] + u * 1024);
            } else {
                int ub = u - 16;
                int n = ub * 16 + srow;
                int klog = (sslot ^ ((n >> 1) & 3)) * 8;
                gload16(Bh + (size_t)n * KD + k0 + klog,
                        (char*)&Bs_h[b][0] + ub * 1024);
            }
        }
    };

    stage(0, 0);
    __syncthreads();
    for (int s = 0; s < NSTEP; s++) {
        int b = s & 1;
        if (s + 1 < NSTEP) stage(s + 1, b ^ 1);

        short8v am_h[2];
#pragma unroll
        for (int mr = 0; mr < 2; mr++) {
            int r = rg * 32 + mr * 16 + lr;
            int s0 = ((2 * hi4 + 0) ^ (r & 7)) * 4;
            int s1 = ((2 * hi4 + 1) ^ (r & 7)) * 4;
            float4 f0 = *(const float4*)&As_f[b][r * 32 + s0];
            float4 f1 = *(const float4*)&As_f[b][r * 32 + s1];
            short8v v;
            v[0] = (short)f2bu(f0.x); v[1] = (short)f2bu(f0.y);
            v[2] = (short)f2bu(f0.z); v[3] = (short)f2bu(f0.w);
            v[4] = (short)f2bu(f1.x); v[5] = (short)f2bu(f1.y);
            v[6] = (short)f2bu(f1.z); v[7] = (short)f2bu(f1.w);
            am_h[mr] = v;
        }
#pragma unroll
        for (int ncc = 0; ncc < 8; ncc += 4) {
            short8v bn_h[4];
#pragma unroll
            for (int j = 0; j < 4; j++) {
                int n = ch * 128 + (ncc + j) * 16 + lr;
                int ko = (hi4 ^ ((n >> 1) & 3)) * 8;
                bn_h[j] = *(const short8v*)&Bs_h[b][n * 32 + ko];
            }
#pragma unroll
            for (int mr = 0; mr < 2; mr++)
#pragma unroll
                for (int j = 0; j < 4; j++)
                    acc[mr][ncc + j] = mfma16(am_h[mr], bn_h[j], acc[mr][ncc + j]);
        }
        __syncthreads();
    }

    unsigned short* OH = ch ? oh1 : oh0;
    const float* v1 = ch ? at2 : ah2;
    const float* v2 = ch ? at3 : ah3;
#pragma unroll
    for (int mr = 0; mr < 2; mr++)
#pragma unroll
        for (int rr = 0; rr < 4; rr++) {
            int row = row0 + rg * 32 + mr * 16 + hi4 * 4 + rr;
            float d0 = 0.f, d1 = 0.f, d2 = 0.f;
#pragma unroll
            for (int nc = 0; nc < 8; nc++) {
                float v = fmaxf(acc[mr][nc][rr], 0.f);
                int col = nc * 16 + lr;
                d0 = fmaf(v, v1[col], d0);
                d1 = fmaf(v, v2[col], d1);
                d2 = ch ? fmaf(v, v, d2) : fmaf(v, ah4[col], d2);
            }
#pragma unroll
            for (int o = 1; o <= 8; o <<= 1) {
                d0 += __shfl_xor(d0, o, 64);
                d1 += __shfl_xor(d1, o, 64);
                d2 += __shfl_xor(d2, o, 64);
            }
            float inv = 1.f;
            if (ch) inv = 1.f / fmaxf(sqrtf(d2), 1e-12f);
#pragma unroll
            for (int nc = 0; nc < 8; nc++) {
                float v = fmaxf(acc[mr][nc][rr], 0.f);
                OH[(size_t)row * 128 + nc * 16 + lr] = f2bu(ch ? v * inv : v);
            }
            if (lr == 0) {
                if (ch == 0) {
                    hb[row] = d0 + 0.25f * d1;
                    eh4o[row] = d2;
                } else {
                    float tav = (d0 + 0.25f * d1) * inv;
                    pta[row] = make_float2(tav, __int_as_float(tidxg[row]));
                }
            }
        }
}

// ---- highway GEMM: 8-wave 256-row block (KD=128, A bf16) ----
// gate=sigmoid(C+bias); o0 = g*(m3[row]?xeh:0) + (1-g)*bf16(A).
__global__ __launch_bounds__(512) void k_mm_hw(
    const unsigned short* __restrict__ Ah, const unsigned short* __restrict__ Bh,
    float* __restrict__ o0, const float* __restrict__ bias,
    const float* __restrict__ xeh, const unsigned* __restrict__ m3f, int M) {
    constexpr int KD = 128;
    constexpr int NSTEP = KD / 32;
    __shared__ unsigned short As_h[2][256 * 32];
    __shared__ unsigned short Bs_h[2][128 * 32];

    int row0 = blockIdx.x * 256;
    if (row0 + 256 > M) row0 = M - 256;
    int tid = threadIdx.x, w = tid >> 6, l = tid & 63;
    int lr = l & 15, hi4 = l >> 4;
    int srow = l >> 2, sslot = l & 3;

    f32x4 acc[2][8];
#pragma unroll
    for (int i = 0; i < 2; i++)
#pragma unroll
        for (int j = 0; j < 8; j++) acc[i][j] = (f32x4){0.f, 0.f, 0.f, 0.f};

    auto stage = [&](int s, int b) {
        int k0 = s * 32;
#pragma unroll
        for (int i = 0; i < 3; i++) {            // 24 units, 3/wave
            int u = w * 3 + i;
            if (u < 16) {                         // A: 16 units of 16 rows
                int row = u * 16 + srow;
                int klog = (sslot ^ ((row >> 1) & 3)) * 8;
                gload16(Ah + (size_t)(row0 + row) * KD + k0 + klog,
                        (char*)&As_h[b][0] + u * 1024);
            } else {                              // B: 8 units of 16 rows
                int ub = u - 16;
                int row = ub * 16 + srow;
                int klog = (sslot ^ ((row >> 1) & 3)) * 8;
                gload16(Bh + (size_t)row * KD + k0 + klog,
                        (char*)&Bs_h[b][0] + ub * 1024);
            }
        }
    };

    stage(0, 0);
    __syncthreads();
    for (int s = 0; s < NSTEP; s++) {
        int b = s & 1;
        if (s + 1 < NSTEP) stage(s + 1, b ^ 1);
        short8v am_h[2];
#pragma unroll
        for (int mr = 0; mr < 2; mr++) {
            int r = w * 32 + mr * 16 + lr;       // r in [0,256)
            int ko = (hi4 ^ ((r >> 1) & 3)) * 8;
            am_h[mr] = *(const short8v*)&As_h[b][r * 32 + ko];
        }
#pragma unroll
        for (int ncc = 0; ncc < 8; ncc += 4) {
            short8v bn_h[4];
#pragma unroll
            for (int j = 0; j < 4; j++) {
                int n = (ncc + j) * 16 + lr;
                int ko = (hi4 ^ ((n >> 1) & 3)) * 8;
                bn_h[j] = *(const short8v*)&Bs_h[b][n * 32 + ko];
            }
#pragma unroll
            for (int mr = 0; mr < 2; mr++)
#pragma unroll
                for (int j = 0; j < 4; j++)
                    acc[mr][ncc + j] = mfma16(am_h[mr], bn_h[j], acc[mr][ncc + j]);
        }
        __syncthreads();
    }

#pragma unroll
    for (int mr = 0; mr < 2; mr++)
#pragma unroll
        for (int rr = 0; rr < 4; rr++) {
            int row = row0 + w * 32 + mr * 16 + hi4 * 4 + rr;
            bool touched = (m3f[row] != 0u);
#pragma unroll
            for (int nc = 0; nc < 8; nc++) {
                int col = nc * 16 + lr;
                float a = acc[mr][nc][rr] + bias[col];
                float g = 1.f / (1.f + expf(-a));
                size_t o = (size_t)row * 128 + col;
                float af = bu2f(Ah[o]);
                float xv = 0.f;
                if (touched) xv = xeh[o];
                o0[o] = g * xv + (1.f - g) * af;
            }
        }
}

__global__ __launch_bounds__(1024) void k_scan(const int* __restrict__ cnt,
                                               int* __restrict__ off,
                                               int* __restrict__ cur, int NC) {
    __shared__ int wt[16];
    __shared__ int sbase;
    int tid = threadIdx.x, w = tid >> 6, lane = tid & 63;
    if (tid == 0) sbase = 0;
    __syncthreads();
    for (int c0 = 0; c0 < NC; c0 += 1024) {
        int c = c0 + tid;
        int v = (c < NC) ? cnt[c] : 0;
        int x = v;
#pragma unroll
        for (int o = 1; o < 64; o <<= 1) {
            int t = __shfl_up(x, o, 64);
            if (lane >= o) x += t;
        }
        if (lane == 63) wt[w] = x;
        __syncthreads();
        int pre = 0, tot = 0;
#pragma unroll
        for (int i = 0; i < 16; i++) {
            int t = wt[i];
            tot += t;
            if (i < w) pre += t;
        }
        int excl = sbase + pre + x - v;
        if (c < NC) { off[c] = excl; cur[c] = excl; }
        __syncthreads();
        if (tid == 0) sbase += tot;
        __syncthreads();
    }
}

// ---- fused level-2 logit + scatter (packed 8B gather + packed 8B write) ----
__global__ __launch_bounds__(256) void k_edgescatter(
    const int* __restrict__ cidx, int* __restrict__ cur,
    const int* __restrict__ hidx, const int* __restrict__ tidx,
    const int* __restrict__ rel, const float2* __restrict__ pta,
    const float* __restrict__ hb, const float* __restrict__ er2,
    float2* __restrict__ e2gs, int E) {
    int i = blockIdx.x * 256 + threadIdx.x;
    if (i >= E) return;
    int pos = atomicAdd(&cur[cidx[i]], 1);
    float2 p = pta[tidx[i]];
    float z2 = p.x + hb[hidx[i]] + 0.5f * er2[rel[i]];
    e2gs[pos] = make_float2(LRELU(z2), p.y);
}

// ---- fused level-2 softmax + spmm + class-dot, one wave/class ----
__global__ __launch_bounds__(256) void k_spmm2(
    const int* __restrict__ off, const int* __restrict__ cnt,
    const float2* __restrict__ e2gs, const unsigned* __restrict__ xrtn_b,
    float* __restrict__ xclass, const float* __restrict__ ac,
    const float* __restrict__ eh4, const int* __restrict__ hclass,
    float* __restrict__ zc, unsigned* __restrict__ m3, int NC) {
    int lane = threadIdx.x & 63;
    int c = blockIdx.x * 4 + (threadIdx.x >> 6);
    if (c >= NC) return;
    int n = cnt[c];
    float a0 = 0.f, a1 = 0.f;
    if (n > 0) {
        int base = off[c];
        float m = -3.4e38f, s = 0.f;
        for (int j = lane; j < n; j += 64) {
            float z = e2gs[base + j].x;
            if (z > m) { s = s * __expf(m - z) + 1.f; m = z; }
            else s += __expf(z - m);
        }
        float M = wredmax(m);
        s = wred(s * __expf(m - M));
        float inv = 1.f / (s + 1e-16f);
        for (int j0 = 0; j0 < n; j0 += 64) {
            int lim = n - j0;
            if (lim > 64) lim = 64;
            float wv = 0.f;
            int g = 0;
            if (lane < lim) {
                float2 pg = e2gs[base + j0 + lane];
                wv = __expf(pg.x - M) * inv;
                g = __float_as_int(pg.y);
            }
            int jj = 0;
            for (; jj + 8 <= lim; jj += 8) {
                float w0 = __shfl(wv, jj + 0), w1 = __shfl(wv, jj + 1);
                float w2 = __shfl(wv, jj + 2), w3 = __shfl(wv, jj + 3);
                float w4 = __shfl(wv, jj + 4), w5 = __shfl(wv, jj + 5);
                float w6 = __shfl(wv, jj + 6), w7 = __shfl(wv, jj + 7);
                unsigned u0 = xrtn_b[(size_t)__shfl(g, jj + 0) * 64 + lane];
                unsigned u1 = xrtn_b[(size_t)__shfl(g, jj + 1) * 64 + lane];
                unsigned u2 = xrtn_b[(size_t)__shfl(g, jj + 2) * 64 + lane];
                unsigned u3 = xrtn_b[(size_t)__shfl(g, jj + 3) * 64 + lane];
                unsigned u4 = xrtn_b[(size_t)__shfl(g, jj + 4) * 64 + lane];
                unsigned u5 = xrtn_b[(size_t)__shfl(g, jj + 5) * 64 + lane];
                unsigned u6 = xrtn_b[(size_t)__shfl(g, jj + 6) * 64 + lane];
                unsigned u7 = xrtn_b[(size_t)__shfl(g, jj + 7) * 64 + lane];
                a0 = fmaf(w0, bu2f((unsigned short)(u0 & 0xffff)), a0);
                a1 = fmaf(w0, bu2f((unsigned short)(u0 >> 16)), a1);
                a0 = fmaf(w1, bu2f((unsigned short)(u1 & 0xffff)), a0);
                a1 = fmaf(w1, bu2f((unsigned short)(u1 >> 16)), a1);
                a0 = fmaf(w2, bu2f((unsigned short)(u2 & 0xffff)), a0);
                a1 = fmaf(w2, bu2f((unsigned short)(u2 >> 16)), a1);
                a0 = fmaf(w3, bu2f((unsigned short)(u3 & 0xffff)), a0);
                a1 = fmaf(w3, bu2f((unsigned short)(u3 >> 16)), a1);
                a0 = fmaf(w4, bu2f((unsigned short)(u4 & 0xffff)), a0);
                a1 = fmaf(w4, bu2f((unsigned short)(u4 >> 16)), a1);
                a0 = fmaf(w5, bu2f((unsigned short)(u5 & 0xffff)), a0);
                a1 = fmaf(w5, bu2f((unsigned short)(u5 >> 16)), a1);
                a0 = fmaf(w6, bu2f((unsigned short)(u6 & 0xffff)), a0);
                a1 = fmaf(w6, bu2f((unsigned short)(u6 >> 16)), a1);
                a0 = fmaf(w7, bu2f((unsigned short)(u7 & 0xffff)), a0);
                a1 = fmaf(w7, bu2f((unsigned short)(u7 >> 16)), a1);
            }
            for (; jj < lim; jj++) {
                float wj = __shfl(wv, jj);
                unsigned u = xrtn_b[(size_t)__shfl(g, jj) * 64 + lane];
                a0 = fmaf(wj, bu2f((unsigned short)(u & 0xffff)), a0);
                a1 = fmaf(wj, bu2f((unsigned short)(u >> 16)), a1);
            }
        }
    }
    *(float2*)&xclass[(size_t)c * 128 + 2 * lane] = make_float2(a0, a1);
    float p = wred(a0 * ac[2 * lane] + a1 * ac[2 * lane + 1]);
    if (lane == 0) {
        int hc = hclass[c];
        float z = LRELU(p + eh4[hc]);
        zc[c] = z;
        atomicMax(&m3[hc], fenc(z));
    }
}

// ---- level 3: class -> head entity ----
__global__ __launch_bounds__(256) void k_class2(
    const int* __restrict__ hclass, float* __restrict__ zc,
    const unsigned* __restrict__ m3, float* __restrict__ s3,
    float* __restrict__ xeh, int NC) {
    int lane = threadIdx.x & 63;
    int c = blockIdx.x * 4 + (threadIdx.x >> 6);
    if (c >= NC) return;
    int hc = hclass[c];
    *(float2*)&xeh[(size_t)hc * 128 + 2 * lane] = make_float2(0.f, 0.f);
    if (lane == 0) {
        float ex = expf(zc[c] - fdec(m3[hc]));
        zc[c] = ex;
        atomicAdd(&s3[hc], ex);
    }
}

__global__ __launch_bounds__(256) void k_class3(
    const int* __restrict__ hclass, const float* __restrict__ zc,
    const float* __restrict__ s3, const float* __restrict__ xclass,
    float* __restrict__ xeh, int NC) {
    int lane = threadIdx.x & 63;
    int c = blockIdx.x * 4 + (threadIdx.x >> 6);
    if (c >= NC) return;
    int hc = hclass[c];
    float gama = zc[c] / (s3[hc] + 1e-16f);
    float v0 = xclass[(size_t)c * 128 + lane], v1 = xclass[(size_t)c * 128 + 64 + lane];
    atomicAdd(&xeh[(size_t)hc * 128 + lane], gama * v0);
    atomicAdd(&xeh[(size_t)hc * 128 + 64 + lane], gama * v1);
}

extern "C" void kernel_launch(void* const* d_in, const int* in_sizes, int n_in,
                              void* d_out, int out_size, void* d_ws, size_t ws_size,
                              hipStream_t stream) {
    (void)n_in; (void)out_size; (void)ws_size;
    const float* xe   = (const float*)d_in[0];
    const int*   eidx = (const int*)d_in[1];
    const int*   rel  = (const int*)d_in[2];
    const float* remb = (const float*)d_in[4];
    const int*   cidx = (const int*)d_in[5];
    const int*   hcls = (const int*)d_in[6];
    const float* ah2  = (const float*)d_in[8];
    const float* ah3  = (const float*)d_in[9];
    const float* ah4  = (const float*)d_in[10];
    const float* at2  = (const float*)d_in[12];
    const float* at3  = (const float*)d_in[13];
    const float* ar2  = (const float*)d_in[15];
    const float* ac   = (const float*)d_in[16];
    const float* wh   = (const float*)d_in[17];
    const float* wt   = (const float*)d_in[18];
    const float* hww  = (const float*)d_in[19];
    const float* hwb  = (const float*)d_in[20];
    float* out = (float*)d_out;

    const int NE = in_sizes[0] / 256;
    const int E  = in_sizes[2];
    const int NR = in_sizes[4] / 128;
    const int NC = in_sizes[6];
    const int* hidx = eidx;
    const int* tidx = eidx + E;

    char* base = (char*)d_ws;
    size_t off0 = 0;
    auto alloc = [&](size_t bytes) -> char* {
        char* r = base + off0;
        off0 = (off0 + bytes + 255) & ~(size_t)255;
        return r;
    };
    float* hb   = (float*)alloc((size_t)NE * 4);
    float* eh4b = (float*)alloc((size_t)NE * 4);
    float2* pta = (float2*)alloc((size_t)NE * 8);
    float* er2b = (float*)alloc((size_t)NR * 4);
    float2* e2gs = (float2*)alloc((size_t)E * 8);
    float* zc   = (float*)alloc((size_t)NC * 4);
    unsigned short* wtb_hi = (unsigned short*)alloc((size_t)256 * 256 * 2);
    unsigned short* hwt_hi = (unsigned short*)alloc((size_t)128 * 128 * 2);
    unsigned short* xrh_hi = (unsigned short*)alloc((size_t)NE * 128 * 2);
    unsigned short* xrtn   = (unsigned short*)alloc((size_t)NE * 128 * 2);
    int* offb = (int*)alloc((size_t)NC * 4);
    int* curb = (int*)alloc((size_t)NC * 4);
    float* xclass = (float*)alloc((size_t)NC * 128 * 4);
    float* xeh    = (float*)alloc((size_t)NE * 128 * 4);  // zeroed per-launch by
    // k_class2 for touched hc only; untouched rows never read (m3 guard).
    size_t zoff = off0;  // everything below is zero-initialized per launch
    unsigned* m3 = (unsigned*)alloc((size_t)NE * 4);
    float* s3    = (float*)alloc((size_t)NE * 4);
    int* cntb    = (int*)alloc((size_t)NC * 4);
    size_t zbytes = off0 - zoff;

    hipMemsetAsync(base + zoff, 0, zbytes, stream);

    // fused prelude: convW + rel + hist
    int nbConv = (256 * 256 + 128 * 128 + 255) / 256;
    int nbRel  = (NR + 3) / 4;
    int nbHist = (E + 255) / 256;
    k_prelude<<<nbConv + nbRel + nbHist, 256, 0, stream>>>(
        wh, wt, hww, wtb_hi, hwt_hi, remb, ar2, er2b, NR, cidx, cntb, E,
        nbConv, nbRel);

    // projection GEMM: 8-wave block, both halves per block, A staged once
    k_mm_proj<<<(NE + 127) / 128, 512, 0, stream>>>(
        xe, wtb_hi, xrh_hi, xrtn, NE,
        ah2, ah3, ah4, at2, at3, hb, eh4b, pta, tidx);

    k_scan<<<1, 1024, 0, stream>>>(cntb, offb, curb, NC);

    // fused level-2 logit + scatter (level-1 softmax cancels vs F.normalize)
    k_edgescatter<<<(E + 255) / 256, 256, 0, stream>>>(
        cidx, curb, hidx, tidx, rel, pta, hb, er2b, e2gs, E);

    k_spmm2<<<(NC + 3) / 4, 256, 0, stream>>>(offb, cntb, e2gs,
                                              (const unsigned*)xrtn, xclass,
                                              ac, eh4b, hcls, zc, m3, NC);
    k_class2<<<(NC + 3) / 4, 256, 0, stream>>>(hcls, zc, m3, s3, xeh, NC);
    k_class3<<<(NC + 3) / 4, 256, 0, stream>>>(hcls, zc, s3, xclass, xeh, NC);

    k_mm_hw<<<(NE + 255) / 256, 512, 0, stream>>>(
        xrh_hi, hwt_hi, out, hwb, xeh, m3, NE);
}